// Round 1
// 561.517 us; speedup vs baseline: 1.0082x; 1.0082x over previous
//
#include <hip/hip_runtime.h>
#include <math.h>

#define Dm 1024
#define Tn 1024
#define Bn 2
#define NTOK 2048
#define HQn 16
#define HKVn 4
#define KDn 64
#define VDn 64
#define Gn 4
#define NE 8
#define CAPn 1024
#define HIDn 2048
#define QKVS 1536   // qkv row stride (elems): q[0,1024) k[1024,1280) v[1280,1536)

using frag_ab = __attribute__((ext_vector_type(8))) short;   // 8 bf16
using f32x4  = __attribute__((ext_vector_type(4))) float;

__device__ __forceinline__ unsigned short f2bf(float f) {
    union { float f; unsigned int u; } v; v.f = f;
    unsigned int r = v.u + 0x7FFFu + ((v.u >> 16) & 1u);
    return (unsigned short)(r >> 16);
}
__device__ __forceinline__ float bf2f(unsigned short b) {
    union { unsigned int u; float f; } v; v.u = ((unsigned int)b) << 16;
    return v.f;
}
__device__ __forceinline__ float gelu_fast(float y) {
    float z = 0.7978845608028654f * (y + 0.044715f * y * y * y);
    float az = fabsf(z);
    float t = __expf(-2.f * az);
    float th = (1.f - t) / (1.f + t);
    th = copysignf(th, z);
    return 0.5f * y * (1.f + th);
}

#define GLOAD16(gp, lp) __builtin_amdgcn_global_load_lds( \
    (const __attribute__((address_space(1))) void*)(gp), \
    (__attribute__((address_space(3))) void*)(lp), 16, 0, 0)

// ---------------- RMSNorm (bf16 out, attention pre-norm) ----------------
__global__ void rmsnorm_bf16_kernel(const float* __restrict__ x, const float* __restrict__ scale,
                                    unsigned short* __restrict__ out) {
    int row = blockIdx.x;
    const float* xr = x + (size_t)row * Dm;
    float ss = 0.f;
    for (int d = threadIdx.x; d < Dm; d += 256) { float v = xr[d]; ss += v * v; }
    __shared__ float red[256];
    red[threadIdx.x] = ss; __syncthreads();
    for (int s = 128; s > 0; s >>= 1) {
        if (threadIdx.x < s) red[threadIdx.x] += red[threadIdx.x + s];
        __syncthreads();
    }
    float inv = rsqrtf(red[0] * (1.f / Dm) + 1e-6f);
    for (int d = threadIdx.x; d < Dm; d += 256)
        out[(size_t)row * Dm + d] = f2bf(xr[d] * inv * scale[d]);
}

// ---------------- Fused RMSNorm (fp32 h2 out) + router logits + top-2 gates ----------------
__global__ void rmsnorm_router_kernel(const float* __restrict__ x2, const float* __restrict__ scale,
                                      const float* __restrict__ rw, const float* __restrict__ rb,
                                      float* __restrict__ h2, int* __restrict__ assign,
                                      float* __restrict__ gate) {
    int row = blockIdx.x;
    const float* xr = x2 + (size_t)row * Dm;
    __shared__ float red[256];
    __shared__ float rowbuf[Dm];
    __shared__ float logits[NE];
    float v4[4]; float ss = 0.f;
    #pragma unroll
    for (int i = 0; i < 4; ++i) { v4[i] = xr[threadIdx.x + 256 * i]; ss += v4[i] * v4[i]; }
    red[threadIdx.x] = ss; __syncthreads();
    for (int s = 128; s > 0; s >>= 1) {
        if (threadIdx.x < s) red[threadIdx.x] += red[threadIdx.x + s];
        __syncthreads();
    }
    float inv = rsqrtf(red[0] * (1.f / Dm) + 1e-6f);
    #pragma unroll
    for (int i = 0; i < 4; ++i) {
        int d = threadIdx.x + 256 * i;
        float h = v4[i] * inv * scale[d];
        h2[(size_t)row * Dm + d] = h;
        rowbuf[d] = h;
    }
    __syncthreads();
    int e = threadIdx.x >> 5, lane32 = threadIdx.x & 31;
    float part = 0.f;
    for (int d = lane32; d < Dm; d += 32) part += rowbuf[d] * rw[(size_t)d * NE + e];
    for (int off = 16; off; off >>= 1) part += __shfl_down(part, off, 32);
    if (lane32 == 0) logits[e] = part + rb[e];
    __syncthreads();
    if (threadIdx.x == 0) {
        int i0 = 0; float m0 = logits[0];
        for (int i = 1; i < NE; ++i) if (logits[i] > m0) { m0 = logits[i]; i0 = i; }
        int i1 = -1; float m1 = -1e30f;
        for (int i = 0; i < NE; ++i) if (i != i0 && logits[i] > m1) { m1 = logits[i]; i1 = i; }
        float e1 = __expf(m1 - m0);
        float s = 1.f + e1;
        assign[row * 2] = i0; assign[row * 2 + 1] = i1;
        gate[row * 2] = 1.f / s; gate[row * 2 + 1] = e1 / s;
    }
}

// ---------------- fp32 [R][Cstride] -> bf16 [Cext][R] transpose+convert ----------------
// Reads input cols [c_base + blockIdx.x*64, ...); writes output rows [blockIdx.x*64, ...).
// Cext = gridDim.x*64 (output rows per expert slab).
__global__ void transpose_convert(const float* __restrict__ in, unsigned short* __restrict__ out,
                                  int R, int Cstride, int c_base) {
    int e = blockIdx.z;
    int Cext = gridDim.x * 64;
    in  += (size_t)e * R * Cstride;
    out += (size_t)e * R * Cext;
    __shared__ float T[64][65];
    int tid = threadIdx.x;
    int r0 = blockIdx.y * 64, c0 = blockIdx.x * 64;
    #pragma unroll
    for (int rep = 0; rep < 4; ++rep) {
        int r = (tid >> 4) + rep * 16;
        int c = (tid & 15) * 4;
        float4 v = *(const float4*)(in + (size_t)(r0 + r) * Cstride + c_base + c0 + c);
        T[r][c] = v.x; T[r][c + 1] = v.y; T[r][c + 2] = v.z; T[r][c + 3] = v.w;
    }
    __syncthreads();
    #pragma unroll
    for (int rep = 0; rep < 4; ++rep) {
        int c = rep * 16 + (tid >> 4);
        int r = (tid & 15) * 4;
        unsigned long long pk = (unsigned long long)f2bf(T[r][c])
                              | ((unsigned long long)f2bf(T[r + 1][c]) << 16)
                              | ((unsigned long long)f2bf(T[r + 2][c]) << 32)
                              | ((unsigned long long)f2bf(T[r + 3][c]) << 48);
        *(unsigned long long*)(out + (size_t)(c0 + c) * R + r0 + r) = pk;
    }
}

// ---------------- generic bf16 MFMA GEMM: C[m][n] = A[m][k] @ Bt[n][k]^T ----------------
// MODE 0: bf16 C.  MODE 1: fp32 C = acc + R (residual).
// LDS chunk swizzle: stage src chunk ^= (lane>>3)&3, read chunk ^= (r16>>1)&3
// -> 2-way max bank aliasing (was 8-way on even rows).
template<int MODE>
__global__ __launch_bounds__(256) void mfma_gemm2(const unsigned short* __restrict__ A,
                                                  const unsigned short* __restrict__ Bt,
                                                  void* __restrict__ Cout,
                                                  const float* __restrict__ R,
                                                  int N, int K) {
    int m0 = blockIdx.y * 128, n0 = blockIdx.x * 128;
    __shared__ unsigned short As[128 * 32];
    __shared__ unsigned short Bs[128 * 32];
    int tid = threadIdx.x, wave = tid >> 6, lane = tid & 63;
    int quad = lane >> 4, r16 = lane & 15;
    int wm = wave & 1, wn = wave >> 1;
    int ch16 = ((lane & 3) ^ ((lane >> 3) & 3)) * 16;      // swizzled source chunk
    int rofs = (quad ^ ((r16 >> 1) & 3)) * 16;             // swizzled read chunk
    f32x4 acc[4][4];
    #pragma unroll
    for (int mt = 0; mt < 4; ++mt)
        #pragma unroll
        for (int nt = 0; nt < 4; ++nt) acc[mt][nt] = (f32x4){0.f, 0.f, 0.f, 0.f};
    const size_t rs = (size_t)K * 2;
    const char* ga0 = (const char*)A  + (size_t)m0 * rs;
    const char* gb0 = (const char*)Bt + (size_t)n0 * rs;
    for (int kk = 0; kk < K; kk += 32) {
        __syncthreads();
        #pragma unroll
        for (int i = 0; i < 2; ++i) {
            int r = wave * 16 + i * 64 + (lane >> 2);
            size_t go = (size_t)r * rs + (size_t)kk * 2 + ch16;
            int lofs = wave * 1024 + i * 4096;
            GLOAD16(ga0 + go, (char*)As + lofs);
            GLOAD16(gb0 + go, (char*)Bs + lofs);
        }
        __syncthreads();
        frag_ab a[4], b[4];
        #pragma unroll
        for (int t = 0; t < 4; ++t) {
            a[t] = *(const frag_ab*)((const char*)As + (wm * 64 + t * 16 + r16) * 64 + rofs);
            b[t] = *(const frag_ab*)((const char*)Bs + (wn * 64 + t * 16 + r16) * 64 + rofs);
        }
        #pragma unroll
        for (int mt = 0; mt < 4; ++mt)
            #pragma unroll
            for (int nt = 0; nt < 4; ++nt)
                acc[mt][nt] = __builtin_amdgcn_mfma_f32_16x16x32_bf16(a[mt], b[nt], acc[mt][nt], 0, 0, 0);
    }
    #pragma unroll
    for (int mt = 0; mt < 4; ++mt)
        #pragma unroll
        for (int nt = 0; nt < 4; ++nt)
            #pragma unroll
            for (int r = 0; r < 4; ++r) {
                int m = m0 + wm * 64 + mt * 16 + quad * 4 + r;
                int n = n0 + wn * 64 + nt * 16 + r16;
                size_t idx = (size_t)m * N + n;
                float v = acc[mt][nt][r];
                if (MODE == 0) ((unsigned short*)Cout)[idx] = f2bf(v);
                else           ((float*)Cout)[idx] = v + R[idx];
            }
}

// ---------------- RoPE on bf16 qkv (in place); q pre-scaled by 0.125*log2e ----------------
__global__ void rope_bf16(unsigned short* __restrict__ p) {
    int idx = blockIdx.x * 256 + threadIdx.x;
    const int QC = NTOK * HQn * 32;
    int i, col, row; float scale;
    if (idx < QC) {
        i = idx & 31; int h = (idx >> 5) & 15; row = idx >> 9;
        col = h * 64 + i; scale = 0.18033688011112042f;  // 0.125 * log2(e)
    } else {
        int r = idx - QC;
        i = r & 31; int h = (r >> 5) & 3; row = r >> 7;
        col = 1024 + h * 64 + i; scale = 1.f;
    }
    int t = row & (Tn - 1);
    size_t base = (size_t)row * QKVS + col;
    float theta = __expf(-(float)i * (1.f / 32.f) * 9.210340371976184f); // 10000^(-i/32)
    float ang = (float)t * theta;
    float c = cosf(ang), s = sinf(ang);
    float x1 = bf2f(p[base]), x2 = bf2f(p[base + 32]);
    p[base]      = f2bf((x1 * c - x2 * s) * scale);
    p[base + 32] = f2bf((x2 * c + x1 * s) * scale);
}

// ---------------- MFMA flash attention ----------------
// grid (Tn/128, HQn, Bn), 256 thr = 4 waves x 32 q-rows. S-steps of 128 cols.
__global__ __launch_bounds__(256) void mfma_attn(const unsigned short* __restrict__ qkv,
                                                 unsigned short* __restrict__ attnb) {
    __shared__ unsigned short lds[32768];
    unsigned short* Ps = lds;
    unsigned short* Ks = lds + 16384;
    unsigned short* Vt = lds + 24576;
    int tid = threadIdx.x, wave = tid >> 6, lane = tid & 63;
    int quad = lane >> 4, r16 = lane & 15;
    int tq0 = blockIdx.x * 128, h = blockIdx.y, b = blockIdx.z;
    int kvh = h >> 2;
    const size_t rowb = QKVS * 2;

    {
        const char* qb = (const char*)(qkv + (size_t)(b * Tn + tq0) * QKVS + h * 64);
        int rloc = lane >> 3, ch = (lane & 7) ^ rloc;
        #pragma unroll
        for (int i = 0; i < 4; ++i) {
            int r0 = wave * 8 + i * 32;
            __builtin_amdgcn_global_load_lds(
                (const __attribute__((address_space(1))) void*)(qb + (size_t)(r0 + rloc) * rowb + ch * 16),
                (__attribute__((address_space(3))) void*)((char*)Vt + r0 * 128), 16, 0, 0);
        }
    }
    __syncthreads();
    frag_ab qf[2][2];
    #pragma unroll
    for (int mt = 0; mt < 2; ++mt)
        #pragma unroll
        for (int ks = 0; ks < 2; ++ks) {
            int m = wave * 32 + mt * 16 + r16;
            int ch = (ks * 4 + quad) ^ (m & 7);
            qf[mt][ks] = *(const frag_ab*)((const char*)Vt + m * 128 + ch * 16);
        }

    float m_i[2][4], l_i[2][4];
    f32x4 O[2][4];
    #pragma unroll
    for (int mt = 0; mt < 2; ++mt) {
        #pragma unroll
        for (int r = 0; r < 4; ++r) { m_i[mt][r] = -1e30f; l_i[mt][r] = 0.f; }
        #pragma unroll
        for (int nt = 0; nt < 4; ++nt) O[mt][nt] = (f32x4){0.f, 0.f, 0.f, 0.f};
    }

    int nst = blockIdx.x + 1;
    for (int st = 0; st < nst; ++st) {
        int s0 = st * 128;
        __syncthreads();
        {
            const char* kb = (const char*)(qkv + (size_t)(b * Tn + s0) * QKVS + 1024 + kvh * 64);
            int rloc = lane >> 3, ch = (lane & 7) ^ rloc;
            #pragma unroll
            for (int i = 0; i < 4; ++i) {
                int r0 = wave * 8 + i * 32;
                __builtin_amdgcn_global_load_lds(
                    (const __attribute__((address_space(1))) void*)(kb + (size_t)(r0 + rloc) * rowb + ch * 16),
                    (__attribute__((address_space(3))) void*)((char*)Ks + r0 * 128), 16, 0, 0);
            }
        }
        {
            const unsigned short* vb = qkv + (size_t)(b * Tn + s0) * QKVS + 1280 + kvh * 64;
            int d4 = (tid & 15) * 4;
            #pragma unroll
            for (int pass = 0; pass < 4; ++pass) {
                int sl = 8 * wave + 2 * (lane >> 4) + pass * 32;
                ushort4 v0 = *(const ushort4*)(vb + (size_t)sl * QKVS + d4);
                ushort4 v1 = *(const ushort4*)(vb + (size_t)(sl + 1) * QKVS + d4);
                unsigned short a0[4] = {v0.x, v0.y, v0.z, v0.w};
                unsigned short a1[4] = {v1.x, v1.y, v1.z, v1.w};
                #pragma unroll
                for (int i = 0; i < 4; ++i) {
                    int d = d4 + i;
                    int col = (((sl >> 3) ^ (d & 15)) << 3) | (sl & 7);
                    *(unsigned int*)(Vt + d * 128 + col) =
                        (unsigned int)a0[i] | ((unsigned int)a1[i] << 16);
                }
            }
        }
        __syncthreads();
        f32x4 Sacc[2][8];
        #pragma unroll
        for (int mt = 0; mt < 2; ++mt)
            #pragma unroll
            for (int nt = 0; nt < 8; ++nt) Sacc[mt][nt] = (f32x4){0.f, 0.f, 0.f, 0.f};
        #pragma unroll
        for (int ks = 0; ks < 2; ++ks) {
            frag_ab kf[8];
            #pragma unroll
            for (int nt = 0; nt < 8; ++nt) {
                int n = nt * 16 + r16;
                int ch = (ks * 4 + quad) ^ (n & 7);
                kf[nt] = *(const frag_ab*)((const char*)Ks + n * 128 + ch * 16);
            }
            #pragma unroll
            for (int mt = 0; mt < 2; ++mt)
                #pragma unroll
                for (int nt = 0; nt < 8; ++nt)
                    Sacc[mt][nt] = __builtin_amdgcn_mfma_f32_16x16x32_bf16(qf[mt][ks], kf[nt], Sacc[mt][nt], 0, 0, 0);
        }
        if (st == nst - 1) {
            #pragma unroll
            for (int mt = 0; mt < 2; ++mt) {
                int trow = wave * 32 + mt * 16 + quad * 4;
                #pragma unroll
                for (int nt = 0; nt < 8; ++nt) {
                    int scol = nt * 16 + r16;
                    #pragma unroll
                    for (int r = 0; r < 4; ++r)
                        if (scol > trow + r) Sacc[mt][nt][r] = -1e30f;
                }
            }
        }
        #pragma unroll
        for (int mt = 0; mt < 2; ++mt) {
            float mx[4];
            #pragma unroll
            for (int r = 0; r < 4; ++r) {
                float m_ = Sacc[mt][0][r];
                #pragma unroll
                for (int nt = 1; nt < 8; ++nt) m_ = fmaxf(m_, Sacc[mt][nt][r]);
                mx[r] = m_;
            }
            #pragma unroll
            for (int off = 1; off < 16; off <<= 1)
                #pragma unroll
                for (int r = 0; r < 4; ++r) mx[r] = fmaxf(mx[r], __shfl_xor(mx[r], off));
            #pragma unroll
            for (int r = 0; r < 4; ++r) {
                float mn = fmaxf(m_i[mt][r], mx[r]);
                float al = exp2f(m_i[mt][r] - mn);
                m_i[mt][r] = mn;
                l_i[mt][r] *= al;
                #pragma unroll
                for (int nt = 0; nt < 4; ++nt) O[mt][nt][r] *= al;
            }
            float rsum[4] = {0.f, 0.f, 0.f, 0.f};
            #pragma unroll
            for (int nt = 0; nt < 8; ++nt)
                #pragma unroll
                for (int r = 0; r < 4; ++r) {
                    float pv = exp2f(Sacc[mt][nt][r] - m_i[mt][r]);
                    Sacc[mt][nt][r] = pv;
                    rsum[r] += pv;
                }
            #pragma unroll
            for (int off = 1; off < 16; off <<= 1)
                #pragma unroll
                for (int r = 0; r < 4; ++r) rsum[r] += __shfl_xor(rsum[r], off);
            #pragma unroll
            for (int r = 0; r < 4; ++r) l_i[mt][r] += rsum[r];
            #pragma unroll
            for (int nt = 0; nt < 8; ++nt) {
                int scol = nt * 16 + r16;
                int chb = scol >> 3;
                #pragma unroll
                for (int r = 0; r < 4; ++r) {
                    int m = wave * 32 + mt * 16 + quad * 4 + r;
                    int col = ((chb ^ (m & 15)) << 3) | (scol & 7);
                    Ps[m * 128 + col] = f2bf(Sacc[mt][nt][r]);
                }
            }
        }
        #pragma unroll
        for (int ks = 0; ks < 4; ++ks) {
            frag_ab pa[2], vf[4];
            #pragma unroll
            for (int mt = 0; mt < 2; ++mt) {
                int m = wave * 32 + mt * 16 + r16;
                int ch = (ks * 4 + quad) ^ (m & 15);
                pa[mt] = *(const frag_ab*)((const char*)Ps + m * 256 + ch * 16);
            }
            #pragma unroll
            for (int nt = 0; nt < 4; ++nt) {
                int n = nt * 16 + r16;
                int ch = (ks * 4 + quad) ^ (n & 15);
                vf[nt] = *(const frag_ab*)((const char*)Vt + n * 256 + ch * 16);
            }
            #pragma unroll
            for (int mt = 0; mt < 2; ++mt)
                #pragma unroll
                for (int nt = 0; nt < 4; ++nt)
                    O[mt][nt] = __builtin_amdgcn_mfma_f32_16x16x32_bf16(pa[mt], vf[nt], O[mt][nt], 0, 0, 0);
        }
    }
    #pragma unroll
    for (int mt = 0; mt < 2; ++mt) {
        float inv[4];
        #pragma unroll
        for (int r = 0; r < 4; ++r) inv[r] = 1.f / l_i[mt][r];
        #pragma unroll
        for (int nt = 0; nt < 4; ++nt)
            #pragma unroll
            for (int r = 0; r < 4; ++r) {
                int t = tq0 + wave * 32 + mt * 16 + quad * 4 + r;
                int c = h * 64 + nt * 16 + r16;
                attnb[(size_t)(b * Tn + t) * Dm + c] = f2bf(O[mt][nt][r] * inv[r]);
            }
    }
}

// ---------------- Capacity scan (single block) ----------------
__global__ void scan_kernel(const int* __restrict__ assign, int* __restrict__ pos,
                            int* __restrict__ limit) {
    __shared__ int cnt[256][16];
    __shared__ int tot[16];
    int tid = threadIdx.x;
    int local[16];
    #pragma unroll
    for (int i = 0; i < 16; ++i) local[i] = 0;
    for (int r = 0; r < 8; ++r) {
        int t = tid * 8 + r;
        local[assign[t * 2]]++;
        local[8 + assign[t * 2 + 1]]++;
    }
    #pragma unroll
    for (int i = 0; i < 16; ++i) cnt[tid][i] = local[i];
    __syncthreads();
    if (tid < 16) {
        int run = 0;
        for (int th = 0; th < 256; ++th) { int v = cnt[th][tid]; cnt[th][tid] = run; run += v; }
        tot[tid] = run;
    }
    __syncthreads();
    int r0[NE], r1[NE];
    #pragma unroll
    for (int e = 0; e < NE; ++e) { r0[e] = cnt[tid][e]; r1[e] = cnt[tid][8 + e]; }
    for (int r = 0; r < 8; ++r) {
        int t = tid * 8 + r;
        int e0 = assign[t * 2], e1 = assign[t * 2 + 1];
        r0[e0]++; pos[t * 2] = r0[e0];
        r1[e1]++; pos[t * 2 + 1] = r0[e1] + r1[e1];
    }
    if (tid == 0)
        for (int e = 0; e < NE; ++e) {
            int C = tot[e] + tot[8 + e];
            limit[e] = C < (CAPn - 1) ? C : (CAPn - 1);
        }
}

// ---------------- Dispatch (fp32 scatter-add onto zeroed buffer) ----------------
// grouped MUST be zeroed first: collision slots need exact sum semantics (R5 post-mortem).
__global__ void dispatch_kernel(const float* __restrict__ h2, const int* __restrict__ assign,
                                const int* __restrict__ pos, float* __restrict__ grouped) {
    int slot = blockIdx.x;
    int p = pos[slot];
    if (p >= CAPn) return;
    int e = assign[slot];
    const float* src = h2 + (size_t)(slot >> 1) * Dm;
    float* dst = grouped + ((size_t)e * CAPn + p) * Dm;
    for (int d = threadIdx.x; d < Dm; d += 256) atomicAdd(&dst[d], src[d]);
}

// ---------------- in-place fp32 row -> bf16 packed into first half of same row ----------------
// One block per 1024-float (4 KB) row; bf16 output occupies bytes [0,2048) of the row.
// Downstream GEMM reads A with row stride 4096 B.
__global__ void convert_inplace(float* __restrict__ buf) {
    float* rp = buf + (size_t)blockIdx.x * Dm;
    float4 v = ((const float4*)rp)[threadIdx.x];
    __syncthreads();   // all reads done before any in-place write
    unsigned long long pk = (unsigned long long)f2bf(v.x)
                          | ((unsigned long long)f2bf(v.y) << 16)
                          | ((unsigned long long)f2bf(v.z) << 32)
                          | ((unsigned long long)f2bf(v.w) << 48);
    ((unsigned long long*)rp)[threadIdx.x] = pk;
}

// ---------------- Fused MoE GEMM: hh = gelu((A@w2half) * (A@w1half)) ----------------
// A: strided grouped (bf16 in first 2 KB of each 4 KB row).  B-tile interleaves
// w1-col / w2-col rows (even/odd) via per-lane source select.  Combined N=2048 per
// half (128-wide blocks); epilogue pairs t1/t2 with shfl_xor(1), even lanes store
// gelu(t2*t1) to the 16 MB half-buffer hh[e][CAPn][1024].  tmp1 never materializes.
__global__ __launch_bounds__(256) void mfma_gemm_fused(const float* __restrict__ grouped,
                                                       const unsigned short* __restrict__ B1t,
                                                       const unsigned short* __restrict__ B2t,
                                                       unsigned short* __restrict__ hh,
                                                       const int* __restrict__ limit) {
    int e = blockIdx.z;
    int m0 = blockIdx.y * 128;
    if (m0 > limit[e]) return;
    int n0 = blockIdx.x * 128;   // combined (interleaved) column
    const char* ga0 = (const char*)grouped + ((size_t)e * CAPn + m0) * 4096;
    const unsigned short* b1 = B1t + (size_t)e * 1024 * Dm;
    const unsigned short* b2 = B2t + (size_t)e * 1024 * Dm;
    unsigned short* Ch = hh + (size_t)e * CAPn * 1024;
    __shared__ unsigned short As[128 * 32];
    __shared__ unsigned short Bs[128 * 32];
    int tid = threadIdx.x, wave = tid >> 6, lane = tid & 63;
    int quad = lane >> 4, r16 = lane & 15;
    int wm = wave & 1, wn = wave >> 1;
    int ch16 = ((lane & 3) ^ ((lane >> 3) & 3)) * 16;
    int rofs = (quad ^ ((r16 >> 1) & 3)) * 16;
    f32x4 acc[4][4];
    #pragma unroll
    for (int mt = 0; mt < 4; ++mt)
        #pragma unroll
        for (int nt = 0; nt < 4; ++nt) acc[mt][nt] = (f32x4){0.f, 0.f, 0.f, 0.f};
    for (int kk = 0; kk < Dm; kk += 32) {
        __syncthreads();
        #pragma unroll
        for (int i = 0; i < 2; ++i) {
            int r = wave * 16 + i * 64 + (lane >> 2);
            int lofs = wave * 1024 + i * 4096;
            GLOAD16(ga0 + (size_t)r * 4096 + (size_t)kk * 2 + ch16, (char*)As + lofs);
            const unsigned short* bb = (r & 1) ? b2 : b1;        // even row=w1, odd=w2
            size_t go = (size_t)((n0 + r) >> 1) * 2048 + (size_t)kk * 2 + ch16;
            GLOAD16((const char*)bb + go, (char*)Bs + lofs);
        }
        __syncthreads();
        frag_ab a[4], b[4];
        #pragma unroll
        for (int t = 0; t < 4; ++t) {
            a[t] = *(const frag_ab*)((const char*)As + (wm * 64 + t * 16 + r16) * 64 + rofs);
            b[t] = *(const frag_ab*)((const char*)Bs + (wn * 64 + t * 16 + r16) * 64 + rofs);
        }
        #pragma unroll
        for (int mt = 0; mt < 4; ++mt)
            #pragma unroll
            for (int nt = 0; nt < 4; ++nt)
                acc[mt][nt] = __builtin_amdgcn_mfma_f32_16x16x32_bf16(a[mt], b[nt], acc[mt][nt], 0, 0, 0);
    }
    #pragma unroll
    for (int mt = 0; mt < 4; ++mt)
        #pragma unroll
        for (int nt = 0; nt < 4; ++nt)
            #pragma unroll
            for (int r = 0; r < 4; ++r) {
                float v = acc[mt][nt][r];          // even lane: t1, odd lane: t2
                float w = __shfl_xor(v, 1);        // partner (uniform exec)
                if (!(r16 & 1)) {
                    int m = m0 + wm * 64 + mt * 16 + quad * 4 + r;
                    int j = (n0 + wn * 64 + nt * 16 + r16) >> 1;
                    Ch[(size_t)m * 1024 + j] = f2bf(gelu_fast(v * w));
                }
            }
}

// ---------------- w3 GEMM: eout = hh @ w3t, 128x64 tiles (2x blocks vs 128x128) ----------------
// A rows come from the two hh half-buffers (k<1024 -> hhA, else hhB).
__global__ __launch_bounds__(256) void mfma_gemm_w3(const unsigned short* __restrict__ hhA,
                                                    const unsigned short* __restrict__ hhB,
                                                    const unsigned short* __restrict__ Bt,
                                                    unsigned short* __restrict__ C,
                                                    const int* __restrict__ limit) {
    int e = blockIdx.z;
    int m0 = blockIdx.y * 128;
    if (m0 > limit[e]) return;
    int n0 = blockIdx.x * 64;
    const char* gaA = (const char*)hhA + ((size_t)e * CAPn + m0) * 2048;
    const char* gaB = (const char*)hhB + ((size_t)e * CAPn + m0) * 2048;
    const char* gb0 = (const char*)Bt + ((size_t)e * 1024 + n0) * 4096;
    C += (size_t)e * CAPn * 1024;
    __shared__ unsigned short As[128 * 32];
    __shared__ unsigned short Bs[64 * 32];
    int tid = threadIdx.x, wave = tid >> 6, lane = tid & 63;
    int quad = lane >> 4, r16 = lane & 15;
    int wm = wave & 1, wn = wave >> 1;
    int ch16 = ((lane & 3) ^ ((lane >> 3) & 3)) * 16;
    int rofs = (quad ^ ((r16 >> 1) & 3)) * 16;
    f32x4 acc[4][2];
    #pragma unroll
    for (int mt = 0; mt < 4; ++mt)
        #pragma unroll
        for (int nt = 0; nt < 2; ++nt) acc[mt][nt] = (f32x4){0.f, 0.f, 0.f, 0.f};
    for (int kk = 0; kk < HIDn; kk += 32) {
        const char* ga = (kk < 1024) ? gaA : gaB;
        size_t kb = (size_t)(kk & 1023) * 2;
        __syncthreads();
        #pragma unroll
        for (int i = 0; i < 2; ++i) {
            int r = wave * 16 + i * 64 + (lane >> 2);
            GLOAD16(ga + (size_t)r * 2048 + kb + ch16, (char*)As + wave * 1024 + i * 4096);
        }
        {
            int r = wave * 16 + (lane >> 2);
            GLOAD16(gb0 + (size_t)r * 4096 + (size_t)kk * 2 + ch16, (char*)Bs + wave * 1024);
        }
        __syncthreads();
        frag_ab a[4], b[2];
        #pragma unroll
        for (int t = 0; t < 4; ++t)
            a[t] = *(const frag_ab*)((const char*)As + (wm * 64 + t * 16 + r16) * 64 + rofs);
        #pragma unroll
        for (int t = 0; t < 2; ++t)
            b[t] = *(const frag_ab*)((const char*)Bs + (wn * 32 + t * 16 + r16) * 64 + rofs);
        #pragma unroll
        for (int mt = 0; mt < 4; ++mt)
            #pragma unroll
            for (int nt = 0; nt < 2; ++nt)
                acc[mt][nt] = __builtin_amdgcn_mfma_f32_16x16x32_bf16(a[mt], b[nt], acc[mt][nt], 0, 0, 0);
    }
    #pragma unroll
    for (int mt = 0; mt < 4; ++mt)
        #pragma unroll
        for (int nt = 0; nt < 2; ++nt)
            #pragma unroll
            for (int r = 0; r < 4; ++r) {
                int m = m0 + wm * 64 + mt * 16 + quad * 4 + r;
                int n = n0 + wn * 32 + nt * 16 + r16;
                C[(size_t)m * 1024 + n] = f2bf(acc[mt][nt][r]);
            }
}

// ---------------- Combine ----------------
__global__ void combine_kernel(const float* __restrict__ x2, const float* __restrict__ h2,
                               const unsigned short* __restrict__ eout, const int* __restrict__ assign,
                               const int* __restrict__ pos, const float* __restrict__ gate,
                               float* __restrict__ out) {
    int t = blockIdx.x;
    int e0 = assign[t * 2], e1 = assign[t * 2 + 1];
    int p0 = pos[t * 2],   p1 = pos[t * 2 + 1];
    float g0 = gate[t * 2], g1 = gate[t * 2 + 1];
    bool k0 = p0 < CAPn, k1 = p1 < CAPn;
    const unsigned short* s0 = eout + ((size_t)e0 * CAPn + p0) * Dm;
    const unsigned short* s1 = eout + ((size_t)e1 * CAPn + p1) * Dm;
    const float* hb = h2 + (size_t)t * Dm;
    for (int d = threadIdx.x; d < Dm; d += 256) {
        float v0 = k0 ? bf2f(s0[d]) : hb[d];
        float v1 = k1 ? bf2f(s1[d]) : hb[d];
        out[(size_t)t * Dm + d] = x2[(size_t)t * Dm + d] + g0 * v0 + g1 * v1;
    }
}

extern "C" void kernel_launch(void* const* d_in, const int* in_sizes, int n_in,
                              void* d_out, int out_size, void* d_ws, size_t ws_size,
                              hipStream_t stream) {
    const float* x        = (const float*)d_in[0];
    const float* wq       = (const float*)d_in[1];
    const float* wk       = (const float*)d_in[2];
    const float* wv       = (const float*)d_in[3];
    const float* wo       = (const float*)d_in[4];
    const float* router_w = (const float*)d_in[5];
    const float* router_b = (const float*)d_in[6];
    const float* w1       = (const float*)d_in[7];
    const float* w2       = (const float*)d_in[8];
    const float* w3       = (const float*)d_in[9];
    const float* n1s      = (const float*)d_in[10];
    const float* n2s      = (const float*)d_in[11];
    float* out = (float*)d_out;
    unsigned char* ws = (unsigned char*)d_ws;
    const size_t MB = 1ull << 20;

    // Workspace (peak 113 MB, timeline-aliased):
    //  attn phase:  h_bf[0,4) qkv[4,10) wqkvt[10,13) attnb[13,17) wot[17,19)
    //  MoE phase:   grouped_f32[0,32) (zeroed; bf16 packed in place after convert)
    //               -> eout bf16 [0,16) after fused gemms
    //  persistent:  x2[32,40) h2[40,48) small[48,49)
    //  weights:     wtA[49,65) wtB[65,81) (HID-half transposed, refilled per half)
    //               -> wt3[49,81) after fused gemms
    //  hh halves:   hhA[81,97) (cols 0..1023)  hhB[97,113) (cols 1024..2047)
    unsigned short* h_bf  = (unsigned short*)(ws + 0 * MB);
    unsigned short* qkv   = (unsigned short*)(ws + 4 * MB);
    unsigned short* wqkvt = (unsigned short*)(ws + 10 * MB);
    unsigned short* attnb = (unsigned short*)(ws + 13 * MB);
    unsigned short* wot   = (unsigned short*)(ws + 17 * MB);
    float* grouped_f32    = (float*)(ws + 0 * MB);
    unsigned short* eout  = (unsigned short*)(ws + 0 * MB);
    float* x2      = (float*)(ws + 32 * MB);
    float* h2      = (float*)(ws + 40 * MB);
    int*   assign  = (int*)  (ws + 48 * MB);
    int*   pos     = (int*)  (ws + 48 * MB + 65536);
    float* gate    = (float*)(ws + 48 * MB + 131072);
    int*   limit   = (int*)  (ws + 48 * MB + 196608);
    unsigned short* wtA = (unsigned short*)(ws + 49 * MB);
    unsigned short* wtB = (unsigned short*)(ws + 65 * MB);
    unsigned short* wt3 = (unsigned short*)(ws + 49 * MB);
    unsigned short* hhA = (unsigned short*)(ws + 81 * MB);
    unsigned short* hhB = (unsigned short*)(ws + 97 * MB);
    (void)in_sizes; (void)n_in; (void)out_size; (void)ws_size;

    // ---- attention half (bf16 MFMA) ----
    transpose_convert<<<dim3(16, 16, 1), 256, 0, stream>>>(wq, wqkvt, Dm, Dm, 0);
    transpose_convert<<<dim3(4, 16, 1), 256, 0, stream>>>(wk, wqkvt + 1024 * 1024, Dm, 256, 0);
    transpose_convert<<<dim3(4, 16, 1), 256, 0, stream>>>(wv, wqkvt + 1280 * 1024, Dm, 256, 0);
    transpose_convert<<<dim3(16, 16, 1), 256, 0, stream>>>(wo, wot, Dm, Dm, 0);
    rmsnorm_bf16_kernel<<<NTOK, 256, 0, stream>>>(x, n1s, h_bf);
    mfma_gemm2<0><<<dim3(QKVS / 128, NTOK / 128), 256, 0, stream>>>(h_bf, wqkvt, qkv, nullptr, QKVS, Dm);
    rope_bf16<<<(NTOK * (HQn + HKVn) * 32) / 256, 256, 0, stream>>>(qkv);
    mfma_attn<<<dim3(Tn / 128, HQn, Bn), 256, 0, stream>>>(qkv, attnb);
    mfma_gemm2<1><<<dim3(Dm / 128, NTOK / 128), 256, 0, stream>>>(attnb, wot, x2, x, Dm, Dm);
    // ---- MoE half ----
    rmsnorm_router_kernel<<<NTOK, 256, 0, stream>>>(x2, n2s, router_w, router_b, h2, assign, gate);
    scan_kernel<<<1, 256, 0, stream>>>(assign, pos, limit);
    hipMemsetAsync(grouped_f32, 0, (size_t)NE * CAPn * Dm * sizeof(float), stream);
    dispatch_kernel<<<NTOK * 2, 256, 0, stream>>>(h2, assign, pos, grouped_f32);
    convert_inplace<<<NE * CAPn, 256, 0, stream>>>(grouped_f32);
    // hh half 0 (hid cols 0..1023): hhA = gelu((A@w2h0) * (A@w1h0))
    transpose_convert<<<dim3(16, 16, NE), 256, 0, stream>>>(w1, wtA, Dm, HIDn, 0);
    transpose_convert<<<dim3(16, 16, NE), 256, 0, stream>>>(w2, wtB, Dm, HIDn, 0);
    mfma_gemm_fused<<<dim3(16, CAPn / 128, NE), 256, 0, stream>>>(grouped_f32, wtA, wtB, hhA, limit);
    // hh half 1 (hid cols 1024..2047)
    transpose_convert<<<dim3(16, 16, NE), 256, 0, stream>>>(w1, wtA, Dm, HIDn, 1024);
    transpose_convert<<<dim3(16, 16, NE), 256, 0, stream>>>(w2, wtB, Dm, HIDn, 1024);
    mfma_gemm_fused<<<dim3(16, CAPn / 128, NE), 256, 0, stream>>>(grouped_f32, wtA, wtB, hhB, limit);
    // eout = hh @ w3
    transpose_convert<<<dim3(16, 32, NE), 256, 0, stream>>>(w3, wt3, HIDn, Dm, 0);
    mfma_gemm_w3<<<dim3(16, CAPn / 128, NE), 256, 0, stream>>>(hhA, hhB, wt3, eout, limit);
    combine_kernel<<<NTOK, 256, 0, stream>>>(x2, h2, eout, assign, pos, gate, out);
}

// Round 3
// 551.471 us; speedup vs baseline: 1.0266x; 1.0182x over previous
//
#include <hip/hip_runtime.h>
#include <math.h>

#define Dm 1024
#define Tn 1024
#define Bn 2
#define NTOK 2048
#define HQn 16
#define HKVn 4
#define KDn 64
#define VDn 64
#define Gn 4
#define NE 8
#define CAPn 1024
#define HIDn 2048
#define QKVS 1536   // qkv row stride (elems): q[0,1024) k[1024,1280) v[1280,1536)

using frag_ab = __attribute__((ext_vector_type(8))) short;   // 8 bf16
using f32x4  = __attribute__((ext_vector_type(4))) float;

__device__ __forceinline__ unsigned short f2bf(float f) {
    union { float f; unsigned int u; } v; v.f = f;
    unsigned int r = v.u + 0x7FFFu + ((v.u >> 16) & 1u);
    return (unsigned short)(r >> 16);
}
__device__ __forceinline__ float bf2f(unsigned short b) {
    union { unsigned int u; float f; } v; v.u = ((unsigned int)b) << 16;
    return v.f;
}
__device__ __forceinline__ float gelu_fast(float y) {
    float z = 0.7978845608028654f * (y + 0.044715f * y * y * y);
    float az = fabsf(z);
    float t = __expf(-2.f * az);
    float th = (1.f - t) / (1.f + t);
    th = copysignf(th, z);
    return 0.5f * y * (1.f + th);
}

#define GLOAD16(gp, lp) __builtin_amdgcn_global_load_lds( \
    (const __attribute__((address_space(1))) void*)(gp), \
    (__attribute__((address_space(3))) void*)(lp), 16, 0, 0)

// Drain this wave's LDS reads before the back-edge barrier (race fix, R2 post-mortem):
// s_barrier does NOT drain lgkmcnt, and the compiler may sink lgkm waits + MFMAs past
// a raw barrier (rule #18).  Without this, a wave can cross the barrier with ds_reads
// in flight while another wave's global_load_lds overwrites the same buffer.
#define LGKM_DRAIN() do { \
    asm volatile("s_waitcnt lgkmcnt(0)" ::: "memory"); \
    __builtin_amdgcn_sched_barrier(0); \
} while (0)

// ---------------- RMSNorm (bf16 out, attention pre-norm) ----------------
__global__ void rmsnorm_bf16_kernel(const float* __restrict__ x, const float* __restrict__ scale,
                                    unsigned short* __restrict__ out) {
    int row = blockIdx.x;
    const float* xr = x + (size_t)row * Dm;
    float ss = 0.f;
    for (int d = threadIdx.x; d < Dm; d += 256) { float v = xr[d]; ss += v * v; }
    __shared__ float red[256];
    red[threadIdx.x] = ss; __syncthreads();
    for (int s = 128; s > 0; s >>= 1) {
        if (threadIdx.x < s) red[threadIdx.x] += red[threadIdx.x + s];
        __syncthreads();
    }
    float inv = rsqrtf(red[0] * (1.f / Dm) + 1e-6f);
    for (int d = threadIdx.x; d < Dm; d += 256)
        out[(size_t)row * Dm + d] = f2bf(xr[d] * inv * scale[d]);
}

// ---------------- Fused RMSNorm (fp32 h2 out) + router logits + top-2 gates ----------------
__global__ void rmsnorm_router_kernel(const float* __restrict__ x2, const float* __restrict__ scale,
                                      const float* __restrict__ rw, const float* __restrict__ rb,
                                      float* __restrict__ h2, int* __restrict__ assign,
                                      float* __restrict__ gate) {
    int row = blockIdx.x;
    const float* xr = x2 + (size_t)row * Dm;
    __shared__ float red[256];
    __shared__ float rowbuf[Dm];
    __shared__ float logits[NE];
    float v4[4]; float ss = 0.f;
    #pragma unroll
    for (int i = 0; i < 4; ++i) { v4[i] = xr[threadIdx.x + 256 * i]; ss += v4[i] * v4[i]; }
    red[threadIdx.x] = ss; __syncthreads();
    for (int s = 128; s > 0; s >>= 1) {
        if (threadIdx.x < s) red[threadIdx.x] += red[threadIdx.x + s];
        __syncthreads();
    }
    float inv = rsqrtf(red[0] * (1.f / Dm) + 1e-6f);
    #pragma unroll
    for (int i = 0; i < 4; ++i) {
        int d = threadIdx.x + 256 * i;
        float h = v4[i] * inv * scale[d];
        h2[(size_t)row * Dm + d] = h;
        rowbuf[d] = h;
    }
    __syncthreads();
    int e = threadIdx.x >> 5, lane32 = threadIdx.x & 31;
    float part = 0.f;
    for (int d = lane32; d < Dm; d += 32) part += rowbuf[d] * rw[(size_t)d * NE + e];
    for (int off = 16; off; off >>= 1) part += __shfl_down(part, off, 32);
    if (lane32 == 0) logits[e] = part + rb[e];
    __syncthreads();
    if (threadIdx.x == 0) {
        int i0 = 0; float m0 = logits[0];
        for (int i = 1; i < NE; ++i) if (logits[i] > m0) { m0 = logits[i]; i0 = i; }
        int i1 = -1; float m1 = -1e30f;
        for (int i = 0; i < NE; ++i) if (i != i0 && logits[i] > m1) { m1 = logits[i]; i1 = i; }
        float e1 = __expf(m1 - m0);
        float s = 1.f + e1;
        assign[row * 2] = i0; assign[row * 2 + 1] = i1;
        gate[row * 2] = 1.f / s; gate[row * 2 + 1] = e1 / s;
    }
}

// ---------------- fp32 [R][Cstride] -> bf16 [Cext][R] transpose+convert ----------------
__global__ void transpose_convert(const float* __restrict__ in, unsigned short* __restrict__ out,
                                  int R, int Cstride, int c_base) {
    int e = blockIdx.z;
    int Cext = gridDim.x * 64;
    in  += (size_t)e * R * Cstride;
    out += (size_t)e * R * Cext;
    __shared__ float T[64][65];
    int tid = threadIdx.x;
    int r0 = blockIdx.y * 64, c0 = blockIdx.x * 64;
    #pragma unroll
    for (int rep = 0; rep < 4; ++rep) {
        int r = (tid >> 4) + rep * 16;
        int c = (tid & 15) * 4;
        float4 v = *(const float4*)(in + (size_t)(r0 + r) * Cstride + c_base + c0 + c);
        T[r][c] = v.x; T[r][c + 1] = v.y; T[r][c + 2] = v.z; T[r][c + 3] = v.w;
    }
    __syncthreads();
    #pragma unroll
    for (int rep = 0; rep < 4; ++rep) {
        int c = rep * 16 + (tid >> 4);
        int r = (tid & 15) * 4;
        unsigned long long pk = (unsigned long long)f2bf(T[r][c])
                              | ((unsigned long long)f2bf(T[r + 1][c]) << 16)
                              | ((unsigned long long)f2bf(T[r + 2][c]) << 32)
                              | ((unsigned long long)f2bf(T[r + 3][c]) << 48);
        *(unsigned long long*)(out + (size_t)(c0 + c) * R + r0 + r) = pk;
    }
}

// ---------------- generic bf16 MFMA GEMM: C[m][n] = A[m][k] @ Bt[n][k]^T ----------------
// 1D grid, XCD chunk-swizzle (T1).  Depth-2 prefetch, counted vmcnt, lgkm-drain race fix.
template<int MODE>
__global__ __launch_bounds__(256) void mfma_gemm2(const unsigned short* __restrict__ A,
                                                  const unsigned short* __restrict__ Bt,
                                                  void* __restrict__ Cout,
                                                  const float* __restrict__ R,
                                                  int N, int K, int nx) {
    int nwg = gridDim.x;
    int swz = (blockIdx.x & 7) * (nwg >> 3) + (blockIdx.x >> 3);
    int bx = swz % nx, by = swz / nx;
    int m0 = by * 128, n0 = bx * 128;
    __shared__ unsigned short As[3][128 * 32];
    __shared__ unsigned short Bs[3][128 * 32];
    int tid = threadIdx.x, wave = tid >> 6, lane = tid & 63;
    int quad = lane >> 4, r16 = lane & 15;
    int wm = wave & 1, wn = wave >> 1;
    int ch16 = ((lane & 3) ^ ((lane >> 3) & 3)) * 16;      // swizzled source chunk
    int rofs = (quad ^ ((r16 >> 1) & 3)) * 16;             // swizzled read chunk
    f32x4 acc[4][4];
    #pragma unroll
    for (int mt = 0; mt < 4; ++mt)
        #pragma unroll
        for (int nt = 0; nt < 4; ++nt) acc[mt][nt] = (f32x4){0.f, 0.f, 0.f, 0.f};
    const size_t rs = (size_t)K * 2;
    const char* ga0 = (const char*)A  + (size_t)m0 * rs;
    const char* gb0 = (const char*)Bt + (size_t)n0 * rs;
    auto stage = [&](int buf, int kk) {
        #pragma unroll
        for (int i = 0; i < 2; ++i) {
            int r = wave * 16 + i * 64 + (lane >> 2);
            size_t go = (size_t)r * rs + (size_t)kk * 2 + ch16;
            int lofs = wave * 1024 + i * 4096;
            GLOAD16(ga0 + go, (char*)As[buf] + lofs);
            GLOAD16(gb0 + go, (char*)Bs[buf] + lofs);
        }
    };
    int nsteps = K >> 5;
    stage(0, 0);
    if (nsteps > 1) stage(1, 32);
    int rd = 0, stg = 2;
    for (int t = 0; t < nsteps; ++t) {
        if (t) __builtin_amdgcn_s_barrier();   // all waves done reading buf (t-1)%3
        if (t + 2 < nsteps) {
            stage(stg, (t + 2) << 5);
            stg = (stg == 2) ? 0 : stg + 1;
            asm volatile("s_waitcnt vmcnt(8)" ::: "memory");   // tile t landed
        } else if (t + 1 < nsteps) {
            asm volatile("s_waitcnt vmcnt(4)" ::: "memory");
        } else {
            asm volatile("s_waitcnt vmcnt(0)" ::: "memory");
        }
        __builtin_amdgcn_s_barrier();          // every wave's tile-t data visible
        asm volatile("" ::: "memory");
        const char* Ab = (const char*)As[rd];
        const char* Bb = (const char*)Bs[rd];
        rd = (rd == 2) ? 0 : rd + 1;
        frag_ab a[4], b[4];
        #pragma unroll
        for (int tt = 0; tt < 4; ++tt) {
            a[tt] = *(const frag_ab*)(Ab + (wm * 64 + tt * 16 + r16) * 64 + rofs);
            b[tt] = *(const frag_ab*)(Bb + (wn * 64 + tt * 16 + r16) * 64 + rofs);
        }
        #pragma unroll
        for (int mt = 0; mt < 4; ++mt)
            #pragma unroll
            for (int nt = 0; nt < 4; ++nt)
                acc[mt][nt] = __builtin_amdgcn_mfma_f32_16x16x32_bf16(a[mt], b[nt], acc[mt][nt], 0, 0, 0);
        LGKM_DRAIN();
    }
    #pragma unroll
    for (int mt = 0; mt < 4; ++mt)
        #pragma unroll
        for (int nt = 0; nt < 4; ++nt)
            #pragma unroll
            for (int r = 0; r < 4; ++r) {
                int m = m0 + wm * 64 + mt * 16 + quad * 4 + r;
                int n = n0 + wn * 64 + nt * 16 + r16;
                size_t idx = (size_t)m * N + n;
                float v = acc[mt][nt][r];
                if (MODE == 0) ((unsigned short*)Cout)[idx] = f2bf(v);
                else           ((float*)Cout)[idx] = v + R[idx];
            }
}

// ---------------- RoPE on bf16 qkv (in place); q pre-scaled by 0.125*log2e ----------------
__global__ void rope_bf16(unsigned short* __restrict__ p) {
    int idx = blockIdx.x * 256 + threadIdx.x;
    const int QC = NTOK * HQn * 32;
    int i, col, row; float scale;
    if (idx < QC) {
        i = idx & 31; int h = (idx >> 5) & 15; row = idx >> 9;
        col = h * 64 + i; scale = 0.18033688011112042f;  // 0.125 * log2(e)
    } else {
        int r = idx - QC;
        i = r & 31; int h = (r >> 5) & 3; row = r >> 7;
        col = 1024 + h * 64 + i; scale = 1.f;
    }
    int t = row & (Tn - 1);
    size_t base = (size_t)row * QKVS + col;
    float theta = __expf(-(float)i * (1.f / 32.f) * 9.210340371976184f); // 10000^(-i/32)
    float ang = (float)t * theta;
    float c = cosf(ang), s = sinf(ang);
    float x1 = bf2f(p[base]), x2 = bf2f(p[base + 32]);
    p[base]      = f2bf((x1 * c - x2 * s) * scale);
    p[base + 32] = f2bf((x2 * c + x1 * s) * scale);
}

// ---------------- MFMA flash attention ----------------
__global__ __launch_bounds__(256) void mfma_attn(const unsigned short* __restrict__ qkv,
                                                 unsigned short* __restrict__ attnb) {
    __shared__ unsigned short lds[32768];
    unsigned short* Ps = lds;
    unsigned short* Ks = lds + 16384;
    unsigned short* Vt = lds + 24576;
    int tid = threadIdx.x, wave = tid >> 6, lane = tid & 63;
    int quad = lane >> 4, r16 = lane & 15;
    int tq0 = blockIdx.x * 128, h = blockIdx.y, b = blockIdx.z;
    int kvh = h >> 2;
    const size_t rowb = QKVS * 2;

    {
        const char* qb = (const char*)(qkv + (size_t)(b * Tn + tq0) * QKVS + h * 64);
        int rloc = lane >> 3, ch = (lane & 7) ^ rloc;
        #pragma unroll
        for (int i = 0; i < 4; ++i) {
            int r0 = wave * 8 + i * 32;
            __builtin_amdgcn_global_load_lds(
                (const __attribute__((address_space(1))) void*)(qb + (size_t)(r0 + rloc) * rowb + ch * 16),
                (__attribute__((address_space(3))) void*)((char*)Vt + r0 * 128), 16, 0, 0);
        }
    }
    __syncthreads();
    frag_ab qf[2][2];
    #pragma unroll
    for (int mt = 0; mt < 2; ++mt)
        #pragma unroll
        for (int ks = 0; ks < 2; ++ks) {
            int m = wave * 32 + mt * 16 + r16;
            int ch = (ks * 4 + quad) ^ (m & 7);
            qf[mt][ks] = *(const frag_ab*)((const char*)Vt + m * 128 + ch * 16);
        }

    float m_i[2][4], l_i[2][4];
    f32x4 O[2][4];
    #pragma unroll
    for (int mt = 0; mt < 2; ++mt) {
        #pragma unroll
        for (int r = 0; r < 4; ++r) { m_i[mt][r] = -1e30f; l_i[mt][r] = 0.f; }
        #pragma unroll
        for (int nt = 0; nt < 4; ++nt) O[mt][nt] = (f32x4){0.f, 0.f, 0.f, 0.f};
    }

    int nst = blockIdx.x + 1;
    for (int st = 0; st < nst; ++st) {
        int s0 = st * 128;
        __syncthreads();
        {
            const char* kb = (const char*)(qkv + (size_t)(b * Tn + s0) * QKVS + 1024 + kvh * 64);
            int rloc = lane >> 3, ch = (lane & 7) ^ rloc;
            #pragma unroll
            for (int i = 0; i < 4; ++i) {
                int r0 = wave * 8 + i * 32;
                __builtin_amdgcn_global_load_lds(
                    (const __attribute__((address_space(1))) void*)(kb + (size_t)(r0 + rloc) * rowb + ch * 16),
                    (__attribute__((address_space(3))) void*)((char*)Ks + r0 * 128), 16, 0, 0);
            }
        }
        {
            const unsigned short* vb = qkv + (size_t)(b * Tn + s0) * QKVS + 1280 + kvh * 64;
            int d4 = (tid & 15) * 4;
            #pragma unroll
            for (int pass = 0; pass < 4; ++pass) {
                int sl = 8 * wave + 2 * (lane >> 4) + pass * 32;
                ushort4 v0 = *(const ushort4*)(vb + (size_t)sl * QKVS + d4);
                ushort4 v1 = *(const ushort4*)(vb + (size_t)(sl + 1) * QKVS + d4);
                unsigned short a0[4] = {v0.x, v0.y, v0.z, v0.w};
                unsigned short a1[4] = {v1.x, v1.y, v1.z, v1.w};
                #pragma unroll
                for (int i = 0; i < 4; ++i) {
                    int d = d4 + i;
                    int col = (((sl >> 3) ^ (d & 15)) << 3) | (sl & 7);
                    *(unsigned int*)(Vt + d * 128 + col) =
                        (unsigned int)a0[i] | ((unsigned int)a1[i] << 16);
                }
            }
        }
        __syncthreads();
        f32x4 Sacc[2][8];
        #pragma unroll
        for (int mt = 0; mt < 2; ++mt)
            #pragma unroll
            for (int nt = 0; nt < 8; ++nt) Sacc[mt][nt] = (f32x4){0.f, 0.f, 0.f, 0.f};
        #pragma unroll
        for (int ks = 0; ks < 2; ++ks) {
            frag_ab kf[8];
            #pragma unroll
            for (int nt = 0; nt < 8; ++nt) {
                int n = nt * 16 + r16;
                int ch = (ks * 4 + quad) ^ (n & 7);
                kf[nt] = *(const frag_ab*)((const char*)Ks + n * 128 + ch * 16);
            }
            #pragma unroll
            for (int mt = 0; mt < 2; ++mt)
                #pragma unroll
                for (int nt = 0; nt < 8; ++nt)
                    Sacc[mt][nt] = __builtin_amdgcn_mfma_f32_16x16x32_bf16(qf[mt][ks], kf[nt], Sacc[mt][nt], 0, 0, 0);
        }
        if (st == nst - 1) {
            #pragma unroll
            for (int mt = 0; mt < 2; ++mt) {
                int trow = wave * 32 + mt * 16 + quad * 4;
                #pragma unroll
                for (int nt = 0; nt < 8; ++nt) {
                    int scol = nt * 16 + r16;
                    #pragma unroll
                    for (int r = 0; r < 4; ++r)
                        if (scol > trow + r) Sacc[mt][nt][r] = -1e30f;
                }
            }
        }
        #pragma unroll
        for (int mt = 0; mt < 2; ++mt) {
            float mx[4];
            #pragma unroll
            for (int r = 0; r < 4; ++r) {
                float m_ = Sacc[mt][0][r];
                #pragma unroll
                for (int nt = 1; nt < 8; ++nt) m_ = fmaxf(m_, Sacc[mt][nt][r]);
                mx[r] = m_;
            }
            #pragma unroll
            for (int off = 1; off < 16; off <<= 1)
                #pragma unroll
                for (int r = 0; r < 4; ++r) mx[r] = fmaxf(mx[r], __shfl_xor(mx[r], off));
            #pragma unroll
            for (int r = 0; r < 4; ++r) {
                float mn = fmaxf(m_i[mt][r], mx[r]);
                float al = exp2f(m_i[mt][r] - mn);
                m_i[mt][r] = mn;
                l_i[mt][r] *= al;
                #pragma unroll
                for (int nt = 0; nt < 4; ++nt) O[mt][nt][r] *= al;
            }
            float rsum[4] = {0.f, 0.f, 0.f, 0.f};
            #pragma unroll
            for (int nt = 0; nt < 8; ++nt)
                #pragma unroll
                for (int r = 0; r < 4; ++r) {
                    float pv = exp2f(Sacc[mt][nt][r] - m_i[mt][r]);
                    Sacc[mt][nt][r] = pv;
                    rsum[r] += pv;
                }
            #pragma unroll
            for (int off = 1; off < 16; off <<= 1)
                #pragma unroll
                for (int r = 0; r < 4; ++r) rsum[r] += __shfl_xor(rsum[r], off);
            #pragma unroll
            for (int r = 0; r < 4; ++r) l_i[mt][r] += rsum[r];
            #pragma unroll
            for (int nt = 0; nt < 8; ++nt) {
                int scol = nt * 16 + r16;
                int chb = scol >> 3;
                #pragma unroll
                for (int r = 0; r < 4; ++r) {
                    int m = wave * 32 + mt * 16 + quad * 4 + r;
                    int col = ((chb ^ (m & 15)) << 3) | (scol & 7);
                    Ps[m * 128 + col] = f2bf(Sacc[mt][nt][r]);
                }
            }
        }
        #pragma unroll
        for (int ks = 0; ks < 4; ++ks) {
            frag_ab pa[2], vf[4];
            #pragma unroll
            for (int mt = 0; mt < 2; ++mt) {
                int m = wave * 32 + mt * 16 + r16;
                int ch = (ks * 4 + quad) ^ (m & 15);
                pa[mt] = *(const frag_ab*)((const char*)Ps + m * 256 + ch * 16);
            }
            #pragma unroll
            for (int nt = 0; nt < 4; ++nt) {
                int n = nt * 16 + r16;
                int ch = (ks * 4 + quad) ^ (n & 15);
                vf[nt] = *(const frag_ab*)((const char*)Vt + n * 256 + ch * 16);
            }
            #pragma unroll
            for (int mt = 0; mt < 2; ++mt)
                #pragma unroll
                for (int nt = 0; nt < 4; ++nt)
                    O[mt][nt] = __builtin_amdgcn_mfma_f32_16x16x32_bf16(pa[mt], vf[nt], O[mt][nt], 0, 0, 0);
        }
    }
    #pragma unroll
    for (int mt = 0; mt < 2; ++mt) {
        float inv[4];
        #pragma unroll
        for (int r = 0; r < 4; ++r) inv[r] = 1.f / l_i[mt][r];
        #pragma unroll
        for (int nt = 0; nt < 4; ++nt)
            #pragma unroll
            for (int r = 0; r < 4; ++r) {
                int t = tq0 + wave * 32 + mt * 16 + quad * 4 + r;
                int c = h * 64 + nt * 16 + r16;
                attnb[(size_t)(b * Tn + t) * Dm + c] = f2bf(O[mt][nt][r] * inv[r]);
            }
    }
}

// ---------------- Capacity scan (single block) ----------------
__global__ void scan_kernel(const int* __restrict__ assign, int* __restrict__ pos,
                            int* __restrict__ limit) {
    __shared__ int cnt[256][16];
    __shared__ int tot[16];
    int tid = threadIdx.x;
    int local[16];
    #pragma unroll
    for (int i = 0; i < 16; ++i) local[i] = 0;
    for (int r = 0; r < 8; ++r) {
        int t = tid * 8 + r;
        local[assign[t * 2]]++;
        local[8 + assign[t * 2 + 1]]++;
    }
    #pragma unroll
    for (int i = 0; i < 16; ++i) cnt[tid][i] = local[i];
    __syncthreads();
    if (tid < 16) {
        int run = 0;
        for (int th = 0; th < 256; ++th) { int v = cnt[th][tid]; cnt[th][tid] = run; run += v; }
        tot[tid] = run;
    }
    __syncthreads();
    int r0[NE], r1[NE];
    #pragma unroll
    for (int e = 0; e < NE; ++e) { r0[e] = cnt[tid][e]; r1[e] = cnt[tid][8 + e]; }
    for (int r = 0; r < 8; ++r) {
        int t = tid * 8 + r;
        int e0 = assign[t * 2], e1 = assign[t * 2 + 1];
        r0[e0]++; pos[t * 2] = r0[e0];
        r1[e1]++; pos[t * 2 + 1] = r0[e1] + r1[e1];
    }
    if (tid == 0)
        for (int e = 0; e < NE; ++e) {
            int C = tot[e] + tot[8 + e];
            limit[e] = C < (CAPn - 1) ? C : (CAPn - 1);
        }
}

// ---------------- Dispatch (fp32 scatter-add onto zeroed buffer) ----------------
__global__ void dispatch_kernel(const float* __restrict__ h2, const int* __restrict__ assign,
                                const int* __restrict__ pos, float* __restrict__ grouped) {
    int slot = blockIdx.x;
    int p = pos[slot];
    if (p >= CAPn) return;
    int e = assign[slot];
    const float* src = h2 + (size_t)(slot >> 1) * Dm;
    float* dst = grouped + ((size_t)e * CAPn + p) * Dm;
    for (int d = threadIdx.x; d < Dm; d += 256) atomicAdd(&dst[d], src[d]);
}

// ---------------- in-place fp32 row -> bf16 packed into first half of same row ----------------
__global__ void convert_inplace(float* __restrict__ buf) {
    float* rp = buf + (size_t)blockIdx.x * Dm;
    float4 v = ((const float4*)rp)[threadIdx.x];
    __syncthreads();   // all reads done before any in-place write
    unsigned long long pk = (unsigned long long)f2bf(v.x)
                          | ((unsigned long long)f2bf(v.y) << 16)
                          | ((unsigned long long)f2bf(v.z) << 32)
                          | ((unsigned long long)f2bf(v.w) << 48);
    ((unsigned long long*)rp)[threadIdx.x] = pk;
}

// ---------------- Fused MoE GEMM: hh = gelu((A@w2half) * (A@w1half)) ----------------
// 1D grid 1024, expert-per-XCD swizzle.  Depth-2 pipeline + lgkm-drain race fix.
__global__ __launch_bounds__(256) void mfma_gemm_fused(const float* __restrict__ grouped,
                                                       const unsigned short* __restrict__ B1t,
                                                       const unsigned short* __restrict__ B2t,
                                                       unsigned short* __restrict__ hh,
                                                       const int* __restrict__ limit) {
    int lin = blockIdx.x;
    int swz = (lin & 7) * (gridDim.x >> 3) + (lin >> 3);   // expert e -> XCD (e)
    int e = swz >> 7;
    int m0 = ((swz >> 4) & 7) * 128;
    if (m0 > limit[e]) return;
    int n0 = (swz & 15) * 128;   // combined (interleaved) column
    const char* ga0 = (const char*)grouped + ((size_t)e * CAPn + m0) * 4096;
    const unsigned short* b1 = B1t + (size_t)e * 1024 * Dm;
    const unsigned short* b2 = B2t + (size_t)e * 1024 * Dm;
    unsigned short* Ch = hh + (size_t)e * CAPn * 1024;
    __shared__ unsigned short As[3][128 * 32];
    __shared__ unsigned short Bs[3][128 * 32];
    int tid = threadIdx.x, wave = tid >> 6, lane = tid & 63;
    int quad = lane >> 4, r16 = lane & 15;
    int wm = wave & 1, wn = wave >> 1;
    int ch16 = ((lane & 3) ^ ((lane >> 3) & 3)) * 16;
    int rofs = (quad ^ ((r16 >> 1) & 3)) * 16;
    f32x4 acc[4][4];
    #pragma unroll
    for (int mt = 0; mt < 4; ++mt)
        #pragma unroll
        for (int nt = 0; nt < 4; ++nt) acc[mt][nt] = (f32x4){0.f, 0.f, 0.f, 0.f};
    auto stage = [&](int buf, int kk) {
        #pragma unroll
        for (int i = 0; i < 2; ++i) {
            int r = wave * 16 + i * 64 + (lane >> 2);
            int lofs = wave * 1024 + i * 4096;
            GLOAD16(ga0 + (size_t)r * 4096 + (size_t)kk * 2 + ch16, (char*)As[buf] + lofs);
            const unsigned short* bb = (r & 1) ? b2 : b1;        // even row=w1, odd=w2
            size_t go = (size_t)((n0 + r) >> 1) * 2048 + (size_t)kk * 2 + ch16;
            GLOAD16((const char*)bb + go, (char*)Bs[buf] + lofs);
        }
    };
    const int nsteps = Dm >> 5;   // 32
    stage(0, 0);
    stage(1, 32);
    int rd = 0, stg = 2;
    for (int t = 0; t < nsteps; ++t) {
        if (t) __builtin_amdgcn_s_barrier();
        if (t + 2 < nsteps) {
            stage(stg, (t + 2) << 5);
            stg = (stg == 2) ? 0 : stg + 1;
            asm volatile("s_waitcnt vmcnt(8)" ::: "memory");
        } else if (t + 1 < nsteps) {
            asm volatile("s_waitcnt vmcnt(4)" ::: "memory");
        } else {
            asm volatile("s_waitcnt vmcnt(0)" ::: "memory");
        }
        __builtin_amdgcn_s_barrier();
        asm volatile("" ::: "memory");
        const char* Ab = (const char*)As[rd];
        const char* Bb = (const char*)Bs[rd];
        rd = (rd == 2) ? 0 : rd + 1;
        frag_ab a[4], b[4];
        #pragma unroll
        for (int tt = 0; tt < 4; ++tt) {
            a[tt] = *(const frag_ab*)(Ab + (wm * 64 + tt * 16 + r16) * 64 + rofs);
            b[tt] = *(const frag_ab*)(Bb + (wn * 64 + tt * 16 + r16) * 64 + rofs);
        }
        #pragma unroll
        for (int mt = 0; mt < 4; ++mt)
            #pragma unroll
            for (int nt = 0; nt < 4; ++nt)
                acc[mt][nt] = __builtin_amdgcn_mfma_f32_16x16x32_bf16(a[mt], b[nt], acc[mt][nt], 0, 0, 0);
        LGKM_DRAIN();
    }
    #pragma unroll
    for (int mt = 0; mt < 4; ++mt)
        #pragma unroll
        for (int nt = 0; nt < 4; ++nt)
            #pragma unroll
            for (int r = 0; r < 4; ++r) {
                float v = acc[mt][nt][r];          // even lane: t1, odd lane: t2
                float w = __shfl_xor(v, 1);        // partner (uniform exec)
                if (!(r16 & 1)) {
                    int m = m0 + wm * 64 + mt * 16 + quad * 4 + r;
                    int j = (n0 + wn * 64 + nt * 16 + r16) >> 1;
                    Ch[(size_t)m * 1024 + j] = f2bf(gelu_fast(v * w));
                }
            }
}

// ---------------- w3 GEMM: eout = hh @ w3t, 128x64 tiles ----------------
// 1D grid 1024, expert-per-XCD swizzle.  Depth-2 pipeline + lgkm-drain race fix.
__global__ __launch_bounds__(256) void mfma_gemm_w3(const unsigned short* __restrict__ hhA,
                                                    const unsigned short* __restrict__ hhB,
                                                    const unsigned short* __restrict__ Bt,
                                                    unsigned short* __restrict__ C,
                                                    const int* __restrict__ limit) {
    int lin = blockIdx.x;
    int swz = (lin & 7) * (gridDim.x >> 3) + (lin >> 3);
    int e = swz >> 7;
    int m0 = ((swz >> 4) & 7) * 128;
    if (m0 > limit[e]) return;
    int n0 = (swz & 15) * 64;
    const char* gaA = (const char*)hhA + ((size_t)e * CAPn + m0) * 2048;
    const char* gaB = (const char*)hhB + ((size_t)e * CAPn + m0) * 2048;
    const char* gb0 = (const char*)Bt + ((size_t)e * 1024 + n0) * 4096;
    C += (size_t)e * CAPn * 1024;
    __shared__ unsigned short As[3][128 * 32];
    __shared__ unsigned short Bs[3][64 * 32];
    int tid = threadIdx.x, wave = tid >> 6, lane = tid & 63;
    int quad = lane >> 4, r16 = lane & 15;
    int wm = wave & 1, wn = wave >> 1;
    int ch16 = ((lane & 3) ^ ((lane >> 3) & 3)) * 16;
    int rofs = (quad ^ ((r16 >> 1) & 3)) * 16;
    f32x4 acc[4][2];
    #pragma unroll
    for (int mt = 0; mt < 4; ++mt)
        #pragma unroll
        for (int nt = 0; nt < 2; ++nt) acc[mt][nt] = (f32x4){0.f, 0.f, 0.f, 0.f};
    auto stage = [&](int buf, int kk) {
        const char* ga = (kk < 1024) ? gaA : gaB;
        size_t kb = (size_t)(kk & 1023) * 2;
        #pragma unroll
        for (int i = 0; i < 2; ++i) {
            int r = wave * 16 + i * 64 + (lane >> 2);
            GLOAD16(ga + (size_t)r * 2048 + kb + ch16, (char*)As[buf] + wave * 1024 + i * 4096);
        }
        int r = wave * 16 + (lane >> 2);
        GLOAD16(gb0 + (size_t)r * 4096 + (size_t)kk * 2 + ch16, (char*)Bs[buf] + wave * 1024);
    };
    const int nsteps = HIDn >> 5;   // 64
    stage(0, 0);
    stage(1, 32);
    int rd = 0, stg = 2;
    for (int t = 0; t < nsteps; ++t) {
        if (t) __builtin_amdgcn_s_barrier();
        if (t + 2 < nsteps) {
            stage(stg, (t + 2) << 5);
            stg = (stg == 2) ? 0 : stg + 1;
            asm volatile("s_waitcnt vmcnt(6)" ::: "memory");
        } else if (t + 1 < nsteps) {
            asm volatile("s_waitcnt vmcnt(3)" ::: "memory");
        } else {
            asm volatile("s_waitcnt vmcnt(0)" ::: "memory");
        }
        __builtin_amdgcn_s_barrier();
        asm volatile("" ::: "memory");
        const char* Ab = (const char*)As[rd];
        const char* Bb = (const char*)Bs[rd];
        rd = (rd == 2) ? 0 : rd + 1;
        frag_ab a[4], b[2];
        #pragma unroll
        for (int tt = 0; tt < 4; ++tt)
            a[tt] = *(const frag_ab*)(Ab + (wm * 64 + tt * 16 + r16) * 64 + rofs);
        #pragma unroll
        for (int tt = 0; tt < 2; ++tt)
            b[tt] = *(const frag_ab*)(Bb + (wn * 32 + tt * 16 + r16) * 64 + rofs);
        #pragma unroll
        for (int mt = 0; mt < 4; ++mt)
            #pragma unroll
            for (int nt = 0; nt < 2; ++nt)
                acc[mt][nt] = __builtin_amdgcn_mfma_f32_16x16x32_bf16(a[mt], b[nt], acc[mt][nt], 0, 0, 0);
        LGKM_DRAIN();
    }
    #pragma unroll
    for (int mt = 0; mt < 4; ++mt)
        #pragma unroll
        for (int nt = 0; nt < 2; ++nt)
            #pragma unroll
            for (int r = 0; r < 4; ++r) {
                int m = m0 + wm * 64 + mt * 16 + quad * 4 + r;
                int n = n0 + wn * 32 + nt * 16 + r16;
                C[(size_t)m * 1024 + n] = f2bf(acc[mt][nt][r]);
            }
}

// ---------------- Combine ----------------
__global__ void combine_kernel(const float* __restrict__ x2, const float* __restrict__ h2,
                               const unsigned short* __restrict__ eout, const int* __restrict__ assign,
                               const int* __restrict__ pos, const float* __restrict__ gate,
                               float* __restrict__ out) {
    int t = blockIdx.x;
    int e0 = assign[t * 2], e1 = assign[t * 2 + 1];
    int p0 = pos[t * 2],   p1 = pos[t * 2 + 1];
    float g0 = gate[t * 2], g1 = gate[t * 2 + 1];
    bool k0 = p0 < CAPn, k1 = p1 < CAPn;
    const unsigned short* s0 = eout + ((size_t)e0 * CAPn + p0) * Dm;
    const unsigned short* s1 = eout + ((size_t)e1 * CAPn + p1) * Dm;
    const float* hb = h2 + (size_t)t * Dm;
    for (int d = threadIdx.x; d < Dm; d += 256) {
        float v0 = k0 ? bf2f(s0[d]) : hb[d];
        float v1 = k1 ? bf2f(s1[d]) : hb[d];
        out[(size_t)t * Dm + d] = x2[(size_t)t * Dm + d] + g0 * v0 + g1 * v1;
    }
}

extern "C" void kernel_launch(void* const* d_in, const int* in_sizes, int n_in,
                              void* d_out, int out_size, void* d_ws, size_t ws_size,
                              hipStream_t stream) {
    const float* x        = (const float*)d_in[0];
    const float* wq       = (const float*)d_in[1];
    const float* wk       = (const float*)d_in[2];
    const float* wv       = (const float*)d_in[3];
    const float* wo       = (const float*)d_in[4];
    const float* router_w = (const float*)d_in[5];
    const float* router_b = (const float*)d_in[6];
    const float* w1       = (const float*)d_in[7];
    const float* w2       = (const float*)d_in[8];
    const float* w3       = (const float*)d_in[9];
    const float* n1s      = (const float*)d_in[10];
    const float* n2s      = (const float*)d_in[11];
    float* out = (float*)d_out;
    unsigned char* ws = (unsigned char*)d_ws;
    const size_t MB = 1ull << 20;

    // Workspace map (unchanged, peak 113 MB)
    unsigned short* h_bf  = (unsigned short*)(ws + 0 * MB);
    unsigned short* qkv   = (unsigned short*)(ws + 4 * MB);
    unsigned short* wqkvt = (unsigned short*)(ws + 10 * MB);
    unsigned short* attnb = (unsigned short*)(ws + 13 * MB);
    unsigned short* wot   = (unsigned short*)(ws + 17 * MB);
    float* grouped_f32    = (float*)(ws + 0 * MB);
    unsigned short* eout  = (unsigned short*)(ws + 0 * MB);
    float* x2      = (float*)(ws + 32 * MB);
    float* h2      = (float*)(ws + 40 * MB);
    int*   assign  = (int*)  (ws + 48 * MB);
    int*   pos     = (int*)  (ws + 48 * MB + 65536);
    float* gate    = (float*)(ws + 48 * MB + 131072);
    int*   limit   = (int*)  (ws + 48 * MB + 196608);
    unsigned short* wtA = (unsigned short*)(ws + 49 * MB);
    unsigned short* wtB = (unsigned short*)(ws + 65 * MB);
    unsigned short* wt3 = (unsigned short*)(ws + 49 * MB);
    unsigned short* hhA = (unsigned short*)(ws + 81 * MB);
    unsigned short* hhB = (unsigned short*)(ws + 97 * MB);
    (void)in_sizes; (void)n_in; (void)out_size; (void)ws_size;

    // ---- attention half (bf16 MFMA) ----
    transpose_convert<<<dim3(16, 16, 1), 256, 0, stream>>>(wq, wqkvt, Dm, Dm, 0);
    transpose_convert<<<dim3(4, 16, 1), 256, 0, stream>>>(wk, wqkvt + 1024 * 1024, Dm, 256, 0);
    transpose_convert<<<dim3(4, 16, 1), 256, 0, stream>>>(wv, wqkvt + 1280 * 1024, Dm, 256, 0);
    transpose_convert<<<dim3(16, 16, 1), 256, 0, stream>>>(wo, wot, Dm, Dm, 0);
    rmsnorm_bf16_kernel<<<NTOK, 256, 0, stream>>>(x, n1s, h_bf);
    mfma_gemm2<0><<<dim3((QKVS / 128) * (NTOK / 128)), 256, 0, stream>>>(h_bf, wqkvt, qkv, nullptr, QKVS, Dm, QKVS / 128);
    rope_bf16<<<(NTOK * (HQn + HKVn) * 32) / 256, 256, 0, stream>>>(qkv);
    mfma_attn<<<dim3(Tn / 128, HQn, Bn), 256, 0, stream>>>(qkv, attnb);
    mfma_gemm2<1><<<dim3((Dm / 128) * (NTOK / 128)), 256, 0, stream>>>(attnb, wot, x2, x, Dm, Dm, Dm / 128);
    // ---- MoE half ----
    rmsnorm_router_kernel<<<NTOK, 256, 0, stream>>>(x2, n2s, router_w, router_b, h2, assign, gate);
    scan_kernel<<<1, 256, 0, stream>>>(assign, pos, limit);
    hipMemsetAsync(grouped_f32, 0, (size_t)NE * CAPn * Dm * sizeof(float), stream);
    dispatch_kernel<<<NTOK * 2, 256, 0, stream>>>(h2, assign, pos, grouped_f32);
    convert_inplace<<<NE * CAPn, 256, 0, stream>>>(grouped_f32);
    // hh half 0 (hid cols 0..1023): hhA = gelu((A@w2h0) * (A@w1h0))
    transpose_convert<<<dim3(16, 16, NE), 256, 0, stream>>>(w1, wtA, Dm, HIDn, 0);
    transpose_convert<<<dim3(16, 16, NE), 256, 0, stream>>>(w2, wtB, Dm, HIDn, 0);
    mfma_gemm_fused<<<dim3(16 * (CAPn / 128) * NE), 256, 0, stream>>>(grouped_f32, wtA, wtB, hhA, limit);
    // hh half 1 (hid cols 1024..2047)
    transpose_convert<<<dim3(16, 16, NE), 256, 0, stream>>>(w1, wtA, Dm, HIDn, 1024);
    transpose_convert<<<dim3(16, 16, NE), 256, 0, stream>>>(w2, wtB, Dm, HIDn, 1024);
    mfma_gemm_fused<<<dim3(16 * (CAPn / 128) * NE), 256, 0, stream>>>(grouped_f32, wtA, wtB, hhB, limit);
    // eout = hh @ w3
    transpose_convert<<<dim3(16, 32, NE), 256, 0, stream>>>(w3, wt3, HIDn, Dm, 0);
    mfma_gemm_w3<<<dim3(16 * (CAPn / 128) * NE), 256, 0, stream>>>(hhA, hhB, wt3, eout, limit);
    combine_kernel<<<NTOK, 256, 0, stream>>>(x2, h2, eout, assign, pos, gate, out);
}

// Round 4
// 537.824 us; speedup vs baseline: 1.0526x; 1.0254x over previous
//
#include <hip/hip_runtime.h>
#include <math.h>

#define Dm 1024
#define Tn 1024
#define Bn 2
#define NTOK 2048
#define HQn 16
#define HKVn 4
#define KDn 64
#define VDn 64
#define Gn 4
#define NE 8
#define CAPn 1024
#define HIDn 2048
#define QKVS 1536   // qkv row stride (elems): q[0,1024) k[1024,1280) v[1280,1536)

using frag_ab = __attribute__((ext_vector_type(8))) short;   // 8 bf16
using f32x4  = __attribute__((ext_vector_type(4))) float;

__device__ __forceinline__ unsigned short f2bf(float f) {
    union { float f; unsigned int u; } v; v.f = f;
    unsigned int r = v.u + 0x7FFFu + ((v.u >> 16) & 1u);
    return (unsigned short)(r >> 16);
}
__device__ __forceinline__ float bf2f(unsigned short b) {
    union { unsigned int u; float f; } v; v.u = ((unsigned int)b) << 16;
    return v.f;
}
__device__ __forceinline__ float gelu_fast(float y) {
    float z = 0.7978845608028654f * (y + 0.044715f * y * y * y);
    float az = fabsf(z);
    float t = __expf(-2.f * az);
    float th = (1.f - t) / (1.f + t);
    th = copysignf(th, z);
    return 0.5f * y * (1.f + th);
}

#define GLOAD16(gp, lp) __builtin_amdgcn_global_load_lds( \
    (const __attribute__((address_space(1))) void*)(gp), \
    (__attribute__((address_space(3))) void*)(lp), 16, 0, 0)

// Drain this wave's LDS reads before the back-edge barrier (race fix, R2 post-mortem):
// s_barrier does NOT drain lgkmcnt, and the compiler may sink lgkm waits + MFMAs past
// a raw barrier (rule #18).  Without this, a wave can cross the barrier with ds_reads
// in flight while another wave's global_load_lds overwrites the same buffer.
#define LGKM_DRAIN() do { \
    asm volatile("s_waitcnt lgkmcnt(0)" ::: "memory"); \
    __builtin_amdgcn_sched_barrier(0); \
} while (0)

// ---------------- RMSNorm (bf16 out, attention pre-norm) ----------------
__global__ void rmsnorm_bf16_kernel(const float* __restrict__ x, const float* __restrict__ scale,
                                    unsigned short* __restrict__ out) {
    int row = blockIdx.x;
    const float* xr = x + (size_t)row * Dm;
    float ss = 0.f;
    for (int d = threadIdx.x; d < Dm; d += 256) { float v = xr[d]; ss += v * v; }
    __shared__ float red[256];
    red[threadIdx.x] = ss; __syncthreads();
    for (int s = 128; s > 0; s >>= 1) {
        if (threadIdx.x < s) red[threadIdx.x] += red[threadIdx.x + s];
        __syncthreads();
    }
    float inv = rsqrtf(red[0] * (1.f / Dm) + 1e-6f);
    for (int d = threadIdx.x; d < Dm; d += 256)
        out[(size_t)row * Dm + d] = f2bf(xr[d] * inv * scale[d]);
}

// ---------------- Fused RMSNorm (fp32 h2 out) + router logits + top-2 gates ----------------
__global__ void rmsnorm_router_kernel(const float* __restrict__ x2, const float* __restrict__ scale,
                                      const float* __restrict__ rw, const float* __restrict__ rb,
                                      float* __restrict__ h2, int* __restrict__ assign,
                                      float* __restrict__ gate) {
    int row = blockIdx.x;
    const float* xr = x2 + (size_t)row * Dm;
    __shared__ float red[256];
    __shared__ float rowbuf[Dm];
    __shared__ float logits[NE];
    float v4[4]; float ss = 0.f;
    #pragma unroll
    for (int i = 0; i < 4; ++i) { v4[i] = xr[threadIdx.x + 256 * i]; ss += v4[i] * v4[i]; }
    red[threadIdx.x] = ss; __syncthreads();
    for (int s = 128; s > 0; s >>= 1) {
        if (threadIdx.x < s) red[threadIdx.x] += red[threadIdx.x + s];
        __syncthreads();
    }
    float inv = rsqrtf(red[0] * (1.f / Dm) + 1e-6f);
    #pragma unroll
    for (int i = 0; i < 4; ++i) {
        int d = threadIdx.x + 256 * i;
        float h = v4[i] * inv * scale[d];
        h2[(size_t)row * Dm + d] = h;
        rowbuf[d] = h;
    }
    __syncthreads();
    int e = threadIdx.x >> 5, lane32 = threadIdx.x & 31;
    float part = 0.f;
    for (int d = lane32; d < Dm; d += 32) part += rowbuf[d] * rw[(size_t)d * NE + e];
    for (int off = 16; off; off >>= 1) part += __shfl_down(part, off, 32);
    if (lane32 == 0) logits[e] = part + rb[e];
    __syncthreads();
    if (threadIdx.x == 0) {
        int i0 = 0; float m0 = logits[0];
        for (int i = 1; i < NE; ++i) if (logits[i] > m0) { m0 = logits[i]; i0 = i; }
        int i1 = -1; float m1 = -1e30f;
        for (int i = 0; i < NE; ++i) if (i != i0 && logits[i] > m1) { m1 = logits[i]; i1 = i; }
        float e1 = __expf(m1 - m0);
        float s = 1.f + e1;
        assign[row * 2] = i0; assign[row * 2 + 1] = i1;
        gate[row * 2] = 1.f / s; gate[row * 2 + 1] = e1 / s;
    }
}

// ---------------- fp32 [R][Cstride] -> bf16 [Cext][R] transpose+convert ----------------
__global__ void transpose_convert(const float* __restrict__ in, unsigned short* __restrict__ out,
                                  int R, int Cstride, int c_base) {
    int e = blockIdx.z;
    int Cext = gridDim.x * 64;
    in  += (size_t)e * R * Cstride;
    out += (size_t)e * R * Cext;
    __shared__ float T[64][65];
    int tid = threadIdx.x;
    int r0 = blockIdx.y * 64, c0 = blockIdx.x * 64;
    #pragma unroll
    for (int rep = 0; rep < 4; ++rep) {
        int r = (tid >> 4) + rep * 16;
        int c = (tid & 15) * 4;
        float4 v = *(const float4*)(in + (size_t)(r0 + r) * Cstride + c_base + c0 + c);
        T[r][c] = v.x; T[r][c + 1] = v.y; T[r][c + 2] = v.z; T[r][c + 3] = v.w;
    }
    __syncthreads();
    #pragma unroll
    for (int rep = 0; rep < 4; ++rep) {
        int c = rep * 16 + (tid >> 4);
        int r = (tid & 15) * 4;
        unsigned long long pk = (unsigned long long)f2bf(T[r][c])
                              | ((unsigned long long)f2bf(T[r + 1][c]) << 16)
                              | ((unsigned long long)f2bf(T[r + 2][c]) << 32)
                              | ((unsigned long long)f2bf(T[r + 3][c]) << 48);
        *(unsigned long long*)(out + (size_t)(c0 + c) * R + r0 + r) = pk;
    }
}

// ---------------- generic bf16 MFMA GEMM: C[m][n] = A[m][k] @ Bt[n][k]^T ----------------
// 1D grid, XCD chunk-swizzle (T1).  Depth-2 prefetch, counted vmcnt, lgkm-drain race fix.
template<int MODE>
__global__ __launch_bounds__(256) void mfma_gemm2(const unsigned short* __restrict__ A,
                                                  const unsigned short* __restrict__ Bt,
                                                  void* __restrict__ Cout,
                                                  const float* __restrict__ R,
                                                  int N, int K, int nx) {
    int nwg = gridDim.x;
    int swz = (blockIdx.x & 7) * (nwg >> 3) + (blockIdx.x >> 3);
    int bx = swz % nx, by = swz / nx;
    int m0 = by * 128, n0 = bx * 128;
    __shared__ unsigned short As[3][128 * 32];
    __shared__ unsigned short Bs[3][128 * 32];
    int tid = threadIdx.x, wave = tid >> 6, lane = tid & 63;
    int quad = lane >> 4, r16 = lane & 15;
    int wm = wave & 1, wn = wave >> 1;
    int ch16 = ((lane & 3) ^ ((lane >> 3) & 3)) * 16;      // swizzled source chunk
    int rofs = (quad ^ ((r16 >> 1) & 3)) * 16;             // swizzled read chunk
    f32x4 acc[4][4];
    #pragma unroll
    for (int mt = 0; mt < 4; ++mt)
        #pragma unroll
        for (int nt = 0; nt < 4; ++nt) acc[mt][nt] = (f32x4){0.f, 0.f, 0.f, 0.f};
    const size_t rs = (size_t)K * 2;
    const char* ga0 = (const char*)A  + (size_t)m0 * rs;
    const char* gb0 = (const char*)Bt + (size_t)n0 * rs;
    auto stage = [&](int buf, int kk) {
        #pragma unroll
        for (int i = 0; i < 2; ++i) {
            int r = wave * 16 + i * 64 + (lane >> 2);
            size_t go = (size_t)r * rs + (size_t)kk * 2 + ch16;
            int lofs = wave * 1024 + i * 4096;
            GLOAD16(ga0 + go, (char*)As[buf] + lofs);
            GLOAD16(gb0 + go, (char*)Bs[buf] + lofs);
        }
    };
    int nsteps = K >> 5;
    stage(0, 0);
    if (nsteps > 1) stage(1, 32);
    int rd = 0, stg = 2;
    for (int t = 0; t < nsteps; ++t) {
        if (t) __builtin_amdgcn_s_barrier();   // all waves done reading buf (t-1)%3
        if (t + 2 < nsteps) {
            stage(stg, (t + 2) << 5);
            stg = (stg == 2) ? 0 : stg + 1;
            asm volatile("s_waitcnt vmcnt(8)" ::: "memory");   // tile t landed
        } else if (t + 1 < nsteps) {
            asm volatile("s_waitcnt vmcnt(4)" ::: "memory");
        } else {
            asm volatile("s_waitcnt vmcnt(0)" ::: "memory");
        }
        __builtin_amdgcn_s_barrier();          // every wave's tile-t data visible
        asm volatile("" ::: "memory");
        const char* Ab = (const char*)As[rd];
        const char* Bb = (const char*)Bs[rd];
        rd = (rd == 2) ? 0 : rd + 1;
        frag_ab a[4], b[4];
        #pragma unroll
        for (int tt = 0; tt < 4; ++tt) {
            a[tt] = *(const frag_ab*)(Ab + (wm * 64 + tt * 16 + r16) * 64 + rofs);
            b[tt] = *(const frag_ab*)(Bb + (wn * 64 + tt * 16 + r16) * 64 + rofs);
        }
        #pragma unroll
        for (int mt = 0; mt < 4; ++mt)
            #pragma unroll
            for (int nt = 0; nt < 4; ++nt)
                acc[mt][nt] = __builtin_amdgcn_mfma_f32_16x16x32_bf16(a[mt], b[nt], acc[mt][nt], 0, 0, 0);
        LGKM_DRAIN();
    }
    #pragma unroll
    for (int mt = 0; mt < 4; ++mt)
        #pragma unroll
        for (int nt = 0; nt < 4; ++nt)
            #pragma unroll
            for (int r = 0; r < 4; ++r) {
                int m = m0 + wm * 64 + mt * 16 + quad * 4 + r;
                int n = n0 + wn * 64 + nt * 16 + r16;
                size_t idx = (size_t)m * N + n;
                float v = acc[mt][nt][r];
                if (MODE == 0) ((unsigned short*)Cout)[idx] = f2bf(v);
                else           ((float*)Cout)[idx] = v + R[idx];
            }
}

// ---------------- RoPE on bf16 qkv (in place); q pre-scaled by 0.125*log2e ----------------
__global__ void rope_bf16(unsigned short* __restrict__ p) {
    int idx = blockIdx.x * 256 + threadIdx.x;
    const int QC = NTOK * HQn * 32;
    int i, col, row; float scale;
    if (idx < QC) {
        i = idx & 31; int h = (idx >> 5) & 15; row = idx >> 9;
        col = h * 64 + i; scale = 0.18033688011112042f;  // 0.125 * log2(e)
    } else {
        int r = idx - QC;
        i = r & 31; int h = (r >> 5) & 3; row = r >> 7;
        col = 1024 + h * 64 + i; scale = 1.f;
    }
    int t = row & (Tn - 1);
    size_t base = (size_t)row * QKVS + col;
    float theta = __expf(-(float)i * (1.f / 32.f) * 9.210340371976184f); // 10000^(-i/32)
    float ang = (float)t * theta;
    float c = cosf(ang), s = sinf(ang);
    float x1 = bf2f(p[base]), x2 = bf2f(p[base + 32]);
    p[base]      = f2bf((x1 * c - x2 * s) * scale);
    p[base + 32] = f2bf((x2 * c + x1 * s) * scale);
}

// ---------------- MFMA flash attention ----------------
// QBLK=64: grid (Tn/64, HQn, Bn) = 512 blocks -> 2 blocks/CU (TLP hides staging).
// 4 waves x 16 q-rows each.  KV steps of 128 cols; block x does (x>>1)+1 steps.
// LDS 48 KB: Ps 64x128, Ks 128x64, Vt 64x128 (d-major).
__global__ __launch_bounds__(256) void mfma_attn(const unsigned short* __restrict__ qkv,
                                                 unsigned short* __restrict__ attnb) {
    __shared__ unsigned short lds[24576];
    unsigned short* Ps = lds;            // 64 x 128
    unsigned short* Ks = lds + 8192;     // 128 x 64
    unsigned short* Vt = lds + 16384;    // 64 x 128
    int tid = threadIdx.x, wave = tid >> 6, lane = tid & 63;
    int quad = lane >> 4, r16 = lane & 15;
    int tq0 = blockIdx.x * 64, h = blockIdx.y, b = blockIdx.z;
    int kvh = h >> 2;
    const size_t rowb = QKVS * 2;

    {   // stage Q (64 rows x 128 B) into Vt scratch
        const char* qb = (const char*)(qkv + (size_t)(b * Tn + tq0) * QKVS + h * 64);
        int rloc = lane >> 3, ch = (lane & 7) ^ rloc;
        #pragma unroll
        for (int i = 0; i < 2; ++i) {
            int r0 = wave * 8 + i * 32;
            GLOAD16(qb + (size_t)(r0 + rloc) * rowb + ch * 16, (char*)Vt + r0 * 128);
        }
    }
    __syncthreads();
    frag_ab qf[2];
    #pragma unroll
    for (int ks = 0; ks < 2; ++ks) {
        int m = wave * 16 + r16;
        int ch = (ks * 4 + quad) ^ (m & 7);
        qf[ks] = *(const frag_ab*)((const char*)Vt + m * 128 + ch * 16);
    }

    float m_i[4], l_i[4];
    f32x4 O[4];
    #pragma unroll
    for (int r = 0; r < 4; ++r) { m_i[r] = -1e30f; l_i[r] = 0.f; }
    #pragma unroll
    for (int nt = 0; nt < 4; ++nt) O[nt] = (f32x4){0.f, 0.f, 0.f, 0.f};

    int nst = (blockIdx.x >> 1) + 1;
    int rel = (blockIdx.x & 1) * 64;     // row offset of this q-tile within last kv tile
    for (int st = 0; st < nst; ++st) {
        int s0 = st * 128;
        __syncthreads();
        {
            const char* kb = (const char*)(qkv + (size_t)(b * Tn + s0) * QKVS + 1024 + kvh * 64);
            int rloc = lane >> 3, ch = (lane & 7) ^ rloc;
            #pragma unroll
            for (int i = 0; i < 4; ++i) {
                int r0 = wave * 8 + i * 32;
                GLOAD16(kb + (size_t)(r0 + rloc) * rowb + ch * 16, (char*)Ks + r0 * 128);
            }
        }
        {
            const unsigned short* vb = qkv + (size_t)(b * Tn + s0) * QKVS + 1280 + kvh * 64;
            int d4 = (tid & 15) * 4;
            #pragma unroll
            for (int pass = 0; pass < 4; ++pass) {
                int sl = 8 * wave + 2 * (lane >> 4) + pass * 32;
                ushort4 v0 = *(const ushort4*)(vb + (size_t)sl * QKVS + d4);
                ushort4 v1 = *(const ushort4*)(vb + (size_t)(sl + 1) * QKVS + d4);
                unsigned short a0[4] = {v0.x, v0.y, v0.z, v0.w};
                unsigned short a1[4] = {v1.x, v1.y, v1.z, v1.w};
                #pragma unroll
                for (int i = 0; i < 4; ++i) {
                    int d = d4 + i;
                    int col = (((sl >> 3) ^ (d & 15)) << 3) | (sl & 7);
                    *(unsigned int*)(Vt + d * 128 + col) =
                        (unsigned int)a0[i] | ((unsigned int)a1[i] << 16);
                }
            }
        }
        __syncthreads();
        f32x4 Sacc[8];
        #pragma unroll
        for (int nt = 0; nt < 8; ++nt) Sacc[nt] = (f32x4){0.f, 0.f, 0.f, 0.f};
        #pragma unroll
        for (int ks = 0; ks < 2; ++ks) {
            frag_ab kf[8];
            #pragma unroll
            for (int nt = 0; nt < 8; ++nt) {
                int n = nt * 16 + r16;
                int ch = (ks * 4 + quad) ^ (n & 7);
                kf[nt] = *(const frag_ab*)((const char*)Ks + n * 128 + ch * 16);
            }
            #pragma unroll
            for (int nt = 0; nt < 8; ++nt)
                Sacc[nt] = __builtin_amdgcn_mfma_f32_16x16x32_bf16(qf[ks], kf[nt], Sacc[nt], 0, 0, 0);
        }
        if (st == nst - 1) {
            int trow = wave * 16 + quad * 4 + rel;
            #pragma unroll
            for (int nt = 0; nt < 8; ++nt) {
                int scol = nt * 16 + r16;
                #pragma unroll
                for (int r = 0; r < 4; ++r)
                    if (scol > trow + r) Sacc[nt][r] = -1e30f;
            }
        }
        {
            float mx[4];
            #pragma unroll
            for (int r = 0; r < 4; ++r) {
                float m_ = Sacc[0][r];
                #pragma unroll
                for (int nt = 1; nt < 8; ++nt) m_ = fmaxf(m_, Sacc[nt][r]);
                mx[r] = m_;
            }
            #pragma unroll
            for (int off = 1; off < 16; off <<= 1)
                #pragma unroll
                for (int r = 0; r < 4; ++r) mx[r] = fmaxf(mx[r], __shfl_xor(mx[r], off));
            #pragma unroll
            for (int r = 0; r < 4; ++r) {
                float mn = fmaxf(m_i[r], mx[r]);
                float al = exp2f(m_i[r] - mn);
                m_i[r] = mn;
                l_i[r] *= al;
                #pragma unroll
                for (int nt = 0; nt < 4; ++nt) O[nt][r] *= al;
            }
            float rsum[4] = {0.f, 0.f, 0.f, 0.f};
            #pragma unroll
            for (int nt = 0; nt < 8; ++nt)
                #pragma unroll
                for (int r = 0; r < 4; ++r) {
                    float pv = exp2f(Sacc[nt][r] - m_i[r]);
                    Sacc[nt][r] = pv;
                    rsum[r] += pv;
                }
            #pragma unroll
            for (int off = 1; off < 16; off <<= 1)
                #pragma unroll
                for (int r = 0; r < 4; ++r) rsum[r] += __shfl_xor(rsum[r], off);
            #pragma unroll
            for (int r = 0; r < 4; ++r) l_i[r] += rsum[r];
            #pragma unroll
            for (int nt = 0; nt < 8; ++nt) {
                int scol = nt * 16 + r16;
                int chb = scol >> 3;
                #pragma unroll
                for (int r = 0; r < 4; ++r) {
                    int m = wave * 16 + quad * 4 + r;
                    int col = ((chb ^ (m & 15)) << 3) | (scol & 7);
                    Ps[m * 128 + col] = f2bf(Sacc[nt][r]);
                }
            }
        }
        #pragma unroll
        for (int ks = 0; ks < 4; ++ks) {
            frag_ab pa, vf[4];
            {
                int m = wave * 16 + r16;
                int ch = (ks * 4 + quad) ^ (m & 15);
                pa = *(const frag_ab*)((const char*)Ps + m * 256 + ch * 16);
            }
            #pragma unroll
            for (int nt = 0; nt < 4; ++nt) {
                int n = nt * 16 + r16;
                int ch = (ks * 4 + quad) ^ (n & 15);
                vf[nt] = *(const frag_ab*)((const char*)Vt + n * 256 + ch * 16);
            }
            #pragma unroll
            for (int nt = 0; nt < 4; ++nt)
                O[nt] = __builtin_amdgcn_mfma_f32_16x16x32_bf16(pa, vf[nt], O[nt], 0, 0, 0);
        }
    }
    {
        float inv[4];
        #pragma unroll
        for (int r = 0; r < 4; ++r) inv[r] = 1.f / l_i[r];
        #pragma unroll
        for (int nt = 0; nt < 4; ++nt)
            #pragma unroll
            for (int r = 0; r < 4; ++r) {
                int t = tq0 + wave * 16 + quad * 4 + r;
                int c = h * 64 + nt * 16 + r16;
                attnb[(size_t)(b * Tn + t) * Dm + c] = f2bf(O[nt][r] * inv[r]);
            }
    }
}

// ---------------- Capacity scan (single block) ----------------
__global__ void scan_kernel(const int* __restrict__ assign, int* __restrict__ pos,
                            int* __restrict__ limit) {
    __shared__ int cnt[256][16];
    __shared__ int tot[16];
    int tid = threadIdx.x;
    int local[16];
    #pragma unroll
    for (int i = 0; i < 16; ++i) local[i] = 0;
    for (int r = 0; r < 8; ++r) {
        int t = tid * 8 + r;
        local[assign[t * 2]]++;
        local[8 + assign[t * 2 + 1]]++;
    }
    #pragma unroll
    for (int i = 0; i < 16; ++i) cnt[tid][i] = local[i];
    __syncthreads();
    if (tid < 16) {
        int run = 0;
        for (int th = 0; th < 256; ++th) { int v = cnt[th][tid]; cnt[th][tid] = run; run += v; }
        tot[tid] = run;
    }
    __syncthreads();
    int r0[NE], r1[NE];
    #pragma unroll
    for (int e = 0; e < NE; ++e) { r0[e] = cnt[tid][e]; r1[e] = cnt[tid][8 + e]; }
    for (int r = 0; r < 8; ++r) {
        int t = tid * 8 + r;
        int e0 = assign[t * 2], e1 = assign[t * 2 + 1];
        r0[e0]++; pos[t * 2] = r0[e0];
        r1[e1]++; pos[t * 2 + 1] = r0[e1] + r1[e1];
    }
    if (tid == 0)
        for (int e = 0; e < NE; ++e) {
            int C = tot[e] + tot[8 + e];
            limit[e] = C < (CAPn - 1) ? C : (CAPn - 1);
        }
}

// ---------------- Dispatch (fp32 scatter-add onto zeroed buffer) ----------------
__global__ void dispatch_kernel(const float* __restrict__ h2, const int* __restrict__ assign,
                                const int* __restrict__ pos, float* __restrict__ grouped) {
    int slot = blockIdx.x;
    int p = pos[slot];
    if (p >= CAPn) return;
    int e = assign[slot];
    const float* src = h2 + (size_t)(slot >> 1) * Dm;
    float* dst = grouped + ((size_t)e * CAPn + p) * Dm;
    for (int d = threadIdx.x; d < Dm; d += 256) atomicAdd(&dst[d], src[d]);
}

// ---------------- in-place fp32 row -> bf16 packed into first half of same row ----------------
__global__ void convert_inplace(float* __restrict__ buf) {
    float* rp = buf + (size_t)blockIdx.x * Dm;
    float4 v = ((const float4*)rp)[threadIdx.x];
    __syncthreads();   // all reads done before any in-place write
    unsigned long long pk = (unsigned long long)f2bf(v.x)
                          | ((unsigned long long)f2bf(v.y) << 16)
                          | ((unsigned long long)f2bf(v.z) << 32)
                          | ((unsigned long long)f2bf(v.w) << 48);
    ((unsigned long long*)rp)[threadIdx.x] = pk;
}

// ---------------- Fused MoE GEMM: hh = gelu((A@w2half) * (A@w1half)) ----------------
// 1D grid 1024, expert-per-XCD swizzle.  Depth-2 pipeline + lgkm-drain race fix.
__global__ __launch_bounds__(256) void mfma_gemm_fused(const float* __restrict__ grouped,
                                                       const unsigned short* __restrict__ B1t,
                                                       const unsigned short* __restrict__ B2t,
                                                       unsigned short* __restrict__ hh,
                                                       const int* __restrict__ limit) {
    int lin = blockIdx.x;
    int swz = (lin & 7) * (gridDim.x >> 3) + (lin >> 3);   // expert e -> XCD (e)
    int e = swz >> 7;
    int m0 = ((swz >> 4) & 7) * 128;
    if (m0 > limit[e]) return;
    int n0 = (swz & 15) * 128;   // combined (interleaved) column
    const char* ga0 = (const char*)grouped + ((size_t)e * CAPn + m0) * 4096;
    const unsigned short* b1 = B1t + (size_t)e * 1024 * Dm;
    const unsigned short* b2 = B2t + (size_t)e * 1024 * Dm;
    unsigned short* Ch = hh + (size_t)e * CAPn * 1024;
    __shared__ unsigned short As[3][128 * 32];
    __shared__ unsigned short Bs[3][128 * 32];
    int tid = threadIdx.x, wave = tid >> 6, lane = tid & 63;
    int quad = lane >> 4, r16 = lane & 15;
    int wm = wave & 1, wn = wave >> 1;
    int ch16 = ((lane & 3) ^ ((lane >> 3) & 3)) * 16;
    int rofs = (quad ^ ((r16 >> 1) & 3)) * 16;
    f32x4 acc[4][4];
    #pragma unroll
    for (int mt = 0; mt < 4; ++mt)
        #pragma unroll
        for (int nt = 0; nt < 4; ++nt) acc[mt][nt] = (f32x4){0.f, 0.f, 0.f, 0.f};
    auto stage = [&](int buf, int kk) {
        #pragma unroll
        for (int i = 0; i < 2; ++i) {
            int r = wave * 16 + i * 64 + (lane >> 2);
            int lofs = wave * 1024 + i * 4096;
            GLOAD16(ga0 + (size_t)r * 4096 + (size_t)kk * 2 + ch16, (char*)As[buf] + lofs);
            const unsigned short* bb = (r & 1) ? b2 : b1;        // even row=w1, odd=w2
            size_t go = (size_t)((n0 + r) >> 1) * 2048 + (size_t)kk * 2 + ch16;
            GLOAD16((const char*)bb + go, (char*)Bs[buf] + lofs);
        }
    };
    const int nsteps = Dm >> 5;   // 32
    stage(0, 0);
    stage(1, 32);
    int rd = 0, stg = 2;
    for (int t = 0; t < nsteps; ++t) {
        if (t) __builtin_amdgcn_s_barrier();
        if (t + 2 < nsteps) {
            stage(stg, (t + 2) << 5);
            stg = (stg == 2) ? 0 : stg + 1;
            asm volatile("s_waitcnt vmcnt(8)" ::: "memory");
        } else if (t + 1 < nsteps) {
            asm volatile("s_waitcnt vmcnt(4)" ::: "memory");
        } else {
            asm volatile("s_waitcnt vmcnt(0)" ::: "memory");
        }
        __builtin_amdgcn_s_barrier();
        asm volatile("" ::: "memory");
        const char* Ab = (const char*)As[rd];
        const char* Bb = (const char*)Bs[rd];
        rd = (rd == 2) ? 0 : rd + 1;
        frag_ab a[4], b[4];
        #pragma unroll
        for (int tt = 0; tt < 4; ++tt) {
            a[tt] = *(const frag_ab*)(Ab + (wm * 64 + tt * 16 + r16) * 64 + rofs);
            b[tt] = *(const frag_ab*)(Bb + (wn * 64 + tt * 16 + r16) * 64 + rofs);
        }
        #pragma unroll
        for (int mt = 0; mt < 4; ++mt)
            #pragma unroll
            for (int nt = 0; nt < 4; ++nt)
                acc[mt][nt] = __builtin_amdgcn_mfma_f32_16x16x32_bf16(a[mt], b[nt], acc[mt][nt], 0, 0, 0);
        LGKM_DRAIN();
    }
    #pragma unroll
    for (int mt = 0; mt < 4; ++mt)
        #pragma unroll
        for (int nt = 0; nt < 4; ++nt)
            #pragma unroll
            for (int r = 0; r < 4; ++r) {
                float v = acc[mt][nt][r];          // even lane: t1, odd lane: t2
                float w = __shfl_xor(v, 1);        // partner (uniform exec)
                if (!(r16 & 1)) {
                    int m = m0 + wm * 64 + mt * 16 + quad * 4 + r;
                    int j = (n0 + wn * 64 + nt * 16 + r16) >> 1;
                    Ch[(size_t)m * 1024 + j] = f2bf(gelu_fast(v * w));
                }
            }
}

// ---------------- w3 GEMM: eout = hh @ w3t, 128x64 tiles ----------------
// 1D grid 1024, expert-per-XCD swizzle.  Depth-2 pipeline + lgkm-drain race fix.
__global__ __launch_bounds__(256) void mfma_gemm_w3(const unsigned short* __restrict__ hhA,
                                                    const unsigned short* __restrict__ hhB,
                                                    const unsigned short* __restrict__ Bt,
                                                    unsigned short* __restrict__ C,
                                                    const int* __restrict__ limit) {
    int lin = blockIdx.x;
    int swz = (lin & 7) * (gridDim.x >> 3) + (lin >> 3);
    int e = swz >> 7;
    int m0 = ((swz >> 4) & 7) * 128;
    if (m0 > limit[e]) return;
    int n0 = (swz & 15) * 64;
    const char* gaA = (const char*)hhA + ((size_t)e * CAPn + m0) * 2048;
    const char* gaB = (const char*)hhB + ((size_t)e * CAPn + m0) * 2048;
    const char* gb0 = (const char*)Bt + ((size_t)e * 1024 + n0) * 4096;
    C += (size_t)e * CAPn * 1024;
    __shared__ unsigned short As[3][128 * 32];
    __shared__ unsigned short Bs[3][64 * 32];
    int tid = threadIdx.x, wave = tid >> 6, lane = tid & 63;
    int quad = lane >> 4, r16 = lane & 15;
    int wm = wave & 1, wn = wave >> 1;
    int ch16 = ((lane & 3) ^ ((lane >> 3) & 3)) * 16;
    int rofs = (quad ^ ((r16 >> 1) & 3)) * 16;
    f32x4 acc[4][2];
    #pragma unroll
    for (int mt = 0; mt < 4; ++mt)
        #pragma unroll
        for (int nt = 0; nt < 2; ++nt) acc[mt][nt] = (f32x4){0.f, 0.f, 0.f, 0.f};
    auto stage = [&](int buf, int kk) {
        const char* ga = (kk < 1024) ? gaA : gaB;
        size_t kb = (size_t)(kk & 1023) * 2;
        #pragma unroll
        for (int i = 0; i < 2; ++i) {
            int r = wave * 16 + i * 64 + (lane >> 2);
            GLOAD16(ga + (size_t)r * 2048 + kb + ch16, (char*)As[buf] + wave * 1024 + i * 4096);
        }
        int r = wave * 16 + (lane >> 2);
        GLOAD16(gb0 + (size_t)r * 4096 + (size_t)kk * 2 + ch16, (char*)Bs[buf] + wave * 1024);
    };
    const int nsteps = HIDn >> 5;   // 64
    stage(0, 0);
    stage(1, 32);
    int rd = 0, stg = 2;
    for (int t = 0; t < nsteps; ++t) {
        if (t) __builtin_amdgcn_s_barrier();
        if (t + 2 < nsteps) {
            stage(stg, (t + 2) << 5);
            stg = (stg == 2) ? 0 : stg + 1;
            asm volatile("s_waitcnt vmcnt(6)" ::: "memory");
        } else if (t + 1 < nsteps) {
            asm volatile("s_waitcnt vmcnt(3)" ::: "memory");
        } else {
            asm volatile("s_waitcnt vmcnt(0)" ::: "memory");
        }
        __builtin_amdgcn_s_barrier();
        asm volatile("" ::: "memory");
        const char* Ab = (const char*)As[rd];
        const char* Bb = (const char*)Bs[rd];
        rd = (rd == 2) ? 0 : rd + 1;
        frag_ab a[4], b[2];
        #pragma unroll
        for (int tt = 0; tt < 4; ++tt)
            a[tt] = *(const frag_ab*)(Ab + (wm * 64 + tt * 16 + r16) * 64 + rofs);
        #pragma unroll
        for (int tt = 0; tt < 2; ++tt)
            b[tt] = *(const frag_ab*)(Bb + (wn * 32 + tt * 16 + r16) * 64 + rofs);
        #pragma unroll
        for (int mt = 0; mt < 4; ++mt)
            #pragma unroll
            for (int nt = 0; nt < 2; ++nt)
                acc[mt][nt] = __builtin_amdgcn_mfma_f32_16x16x32_bf16(a[mt], b[nt], acc[mt][nt], 0, 0, 0);
        LGKM_DRAIN();
    }
    #pragma unroll
    for (int mt = 0; mt < 4; ++mt)
        #pragma unroll
        for (int nt = 0; nt < 2; ++nt)
            #pragma unroll
            for (int r = 0; r < 4; ++r) {
                int m = m0 + wm * 64 + mt * 16 + quad * 4 + r;
                int n = n0 + wn * 32 + nt * 16 + r16;
                C[(size_t)m * 1024 + n] = f2bf(acc[mt][nt][r]);
            }
}

// ---------------- Combine ----------------
__global__ void combine_kernel(const float* __restrict__ x2, const float* __restrict__ h2,
                               const unsigned short* __restrict__ eout, const int* __restrict__ assign,
                               const int* __restrict__ pos, const float* __restrict__ gate,
                               float* __restrict__ out) {
    int t = blockIdx.x;
    int e0 = assign[t * 2], e1 = assign[t * 2 + 1];
    int p0 = pos[t * 2],   p1 = pos[t * 2 + 1];
    float g0 = gate[t * 2], g1 = gate[t * 2 + 1];
    bool k0 = p0 < CAPn, k1 = p1 < CAPn;
    const unsigned short* s0 = eout + ((size_t)e0 * CAPn + p0) * Dm;
    const unsigned short* s1 = eout + ((size_t)e1 * CAPn + p1) * Dm;
    const float* hb = h2 + (size_t)t * Dm;
    for (int d = threadIdx.x; d < Dm; d += 256) {
        float v0 = k0 ? bf2f(s0[d]) : hb[d];
        float v1 = k1 ? bf2f(s1[d]) : hb[d];
        out[(size_t)t * Dm + d] = x2[(size_t)t * Dm + d] + g0 * v0 + g1 * v1;
    }
}

extern "C" void kernel_launch(void* const* d_in, const int* in_sizes, int n_in,
                              void* d_out, int out_size, void* d_ws, size_t ws_size,
                              hipStream_t stream) {
    const float* x        = (const float*)d_in[0];
    const float* wq       = (const float*)d_in[1];
    const float* wk       = (const float*)d_in[2];
    const float* wv       = (const float*)d_in[3];
    const float* wo       = (const float*)d_in[4];
    const float* router_w = (const float*)d_in[5];
    const float* router_b = (const float*)d_in[6];
    const float* w1       = (const float*)d_in[7];
    const float* w2       = (const float*)d_in[8];
    const float* w3       = (const float*)d_in[9];
    const float* n1s      = (const float*)d_in[10];
    const float* n2s      = (const float*)d_in[11];
    float* out = (float*)d_out;
    unsigned char* ws = (unsigned char*)d_ws;
    const size_t MB = 1ull << 20;

    // Workspace map (unchanged, peak 113 MB)
    unsigned short* h_bf  = (unsigned short*)(ws + 0 * MB);
    unsigned short* qkv   = (unsigned short*)(ws + 4 * MB);
    unsigned short* wqkvt = (unsigned short*)(ws + 10 * MB);
    unsigned short* attnb = (unsigned short*)(ws + 13 * MB);
    unsigned short* wot   = (unsigned short*)(ws + 17 * MB);
    float* grouped_f32    = (float*)(ws + 0 * MB);
    unsigned short* eout  = (unsigned short*)(ws + 0 * MB);
    float* x2      = (float*)(ws + 32 * MB);
    float* h2      = (float*)(ws + 40 * MB);
    int*   assign  = (int*)  (ws + 48 * MB);
    int*   pos     = (int*)  (ws + 48 * MB + 65536);
    float* gate    = (float*)(ws + 48 * MB + 131072);
    int*   limit   = (int*)  (ws + 48 * MB + 196608);
    unsigned short* wtA = (unsigned short*)(ws + 49 * MB);
    unsigned short* wtB = (unsigned short*)(ws + 65 * MB);
    unsigned short* wt3 = (unsigned short*)(ws + 49 * MB);
    unsigned short* hhA = (unsigned short*)(ws + 81 * MB);
    unsigned short* hhB = (unsigned short*)(ws + 97 * MB);
    (void)in_sizes; (void)n_in; (void)out_size; (void)ws_size;

    // ---- attention half (bf16 MFMA) ----
    transpose_convert<<<dim3(16, 16, 1), 256, 0, stream>>>(wq, wqkvt, Dm, Dm, 0);
    transpose_convert<<<dim3(4, 16, 1), 256, 0, stream>>>(wk, wqkvt + 1024 * 1024, Dm, 256, 0);
    transpose_convert<<<dim3(4, 16, 1), 256, 0, stream>>>(wv, wqkvt + 1280 * 1024, Dm, 256, 0);
    transpose_convert<<<dim3(16, 16, 1), 256, 0, stream>>>(wo, wot, Dm, Dm, 0);
    rmsnorm_bf16_kernel<<<NTOK, 256, 0, stream>>>(x, n1s, h_bf);
    mfma_gemm2<0><<<dim3((QKVS / 128) * (NTOK / 128)), 256, 0, stream>>>(h_bf, wqkvt, qkv, nullptr, QKVS, Dm, QKVS / 128);
    rope_bf16<<<(NTOK * (HQn + HKVn) * 32) / 256, 256, 0, stream>>>(qkv);
    mfma_attn<<<dim3(Tn / 64, HQn, Bn), 256, 0, stream>>>(qkv, attnb);
    mfma_gemm2<1><<<dim3((Dm / 128) * (NTOK / 128)), 256, 0, stream>>>(attnb, wot, x2, x, Dm, Dm, Dm / 128);
    // ---- MoE half ----
    rmsnorm_router_kernel<<<NTOK, 256, 0, stream>>>(x2, n2s, router_w, router_b, h2, assign, gate);
    scan_kernel<<<1, 256, 0, stream>>>(assign, pos, limit);
    hipMemsetAsync(grouped_f32, 0, (size_t)NE * CAPn * Dm * sizeof(float), stream);
    dispatch_kernel<<<NTOK * 2, 256, 0, stream>>>(h2, assign, pos, grouped_f32);
    convert_inplace<<<NE * CAPn, 256, 0, stream>>>(grouped_f32);
    // hh half 0 (hid cols 0..1023): hhA = gelu((A@w2h0) * (A@w1h0))
    transpose_convert<<<dim3(16, 16, NE), 256, 0, stream>>>(w1, wtA, Dm, HIDn, 0);
    transpose_convert<<<dim3(16, 16, NE), 256, 0, stream>>>(w2, wtB, Dm, HIDn, 0);
    mfma_gemm_fused<<<dim3(16 * (CAPn / 128) * NE), 256, 0, stream>>>(grouped_f32, wtA, wtB, hhA, limit);
    // hh half 1 (hid cols 1024..2047)
    transpose_convert<<<dim3(16, 16, NE), 256, 0, stream>>>(w1, wtA, Dm, HIDn, 1024);
    transpose_convert<<<dim3(16, 16, NE), 256, 0, stream>>>(w2, wtB, Dm, HIDn, 1024);
    mfma_gemm_fused<<<dim3(16 * (CAPn / 128) * NE), 256, 0, stream>>>(grouped_f32, wtA, wtB, hhB, limit);
    // eout = hh @ w3
    transpose_convert<<<dim3(16, 32, NE), 256, 0, stream>>>(w3, wt3, HIDn, Dm, 0);
    mfma_gemm_w3<<<dim3(16 * (CAPn / 128) * NE), 256, 0, stream>>>(hhA, hhB, wt3, eout, limit);
    combine_kernel<<<NTOK, 256, 0, stream>>>(x2, h2, eout, assign, pos, gate, out);
}